// Round 3
// baseline (484.951 us; speedup 1.0000x reference)
//
#include <hip/hip_runtime.h>
#include <cmath>

#define NN    4096
#define FIN   32
#define KSEL  39      // neighbors kept (top-40 minus self)
#define PP    22
#define PPAD  24
#define FOUT  48
#define WPB   2       // waves per block
#define QW    4       // queries per wave
#define CAP   128     // candidate cap per query (fallback if exceeded)
#define WCOLS 32      // combined weight columns: [Wf(22) | pad(2) | Ws(4) | pad(4)]

#define WSYNC() asm volatile("s_waitcnt lgkmcnt(0)" ::: "memory")

typedef float f32x2 __attribute__((ext_vector_type(2)));

__device__ __forceinline__ int lane_prefix(unsigned long long m) {
    return __builtin_amdgcn_mbcnt_hi((unsigned)(m >> 32),
           __builtin_amdgcn_mbcnt_lo((unsigned)m, 0));
}

// ---------------- precompute: 4 threads per point, LDS-staged weights ------------
// Also emits pair-packed coords: per pair group g (points 2g,2g+1):
//   cpack[b][g] = [x0,x1,y0,y1, z0,z1,w0,w1]  (two float4 loads per pair in gn_main)
__global__ __launch_bounds__(256) void gn_pre(
    const float* __restrict__ x,
    const float* __restrict__ Wf, const float* __restrict__ bf,
    const float* __restrict__ Ws, const float* __restrict__ bs,
    float* __restrict__ coords4, float* __restrict__ feats,
    float* __restrict__ sqn, float* __restrict__ cpack)
{
    __shared__ __align__(16) float sW[FIN * WCOLS];
    __shared__ float sB[WCOLS];

    int t = threadIdx.x;
    for (int idx = t; idx < FIN * WCOLS; idx += 256) {
        int i = idx >> 5, c = idx & 31;
        float v = 0.f;
        if (c < PP) v = Wf[i * PP + c];
        else if (c >= 24 && c < 28) v = Ws[i * 4 + (c - 24)];
        sW[idx] = v;
    }
    if (t < WCOLS) {
        float v = 0.f;
        if (t < PP) v = bf[t];
        else if (t >= 24 && t < 28) v = bs[t - 24];
        sB[t] = v;
    }
    __syncthreads();

    int gid = blockIdx.x * 256 + t;
    int p = gid >> 2;          // point
    int h = gid & 3;           // column strip
    int c0 = h * 8;

    const float4* xr4 = (const float4*)(x + (size_t)p * FIN);
    float acc[8];
    #pragma unroll
    for (int k = 0; k < 8; ++k) acc[k] = sB[c0 + k];

    // accumulate over i ascending -- bit-identical order to reference kernel
    #pragma unroll
    for (int i = 0; i < 8; ++i) {
        float4 xt = xr4[i];
        const float* w0 = sW + (4 * i + 0) * WCOLS + c0;
        const float* w1 = sW + (4 * i + 1) * WCOLS + c0;
        const float* w2 = sW + (4 * i + 2) * WCOLS + c0;
        const float* w3 = sW + (4 * i + 3) * WCOLS + c0;
        #pragma unroll
        for (int k = 0; k < 8; ++k) acc[k] = fmaf(xt.x, w0[k], acc[k]);
        #pragma unroll
        for (int k = 0; k < 8; ++k) acc[k] = fmaf(xt.y, w1[k], acc[k]);
        #pragma unroll
        for (int k = 0; k < 8; ++k) acc[k] = fmaf(xt.z, w2[k], acc[k]);
        #pragma unroll
        for (int k = 0; k < 8; ++k) acc[k] = fmaf(xt.w, w3[k], acc[k]);
    }

    if (h < 3) {
        float4* fw = (float4*)(feats + (size_t)p * PPAD + c0);
        fw[0] = make_float4(acc[0], acc[1], acc[2], acc[3]);
        fw[1] = make_float4(acc[4], acc[5], acc[6], acc[7]);   // h=2: cols 22,23 are exact 0
    } else {
        ((float4*)coords4)[p] = make_float4(acc[0], acc[1], acc[2], acc[3]);
        sqn[p] = fmaf(acc[0], acc[0], fmaf(acc[1], acc[1],
                 fmaf(acc[2], acc[2], acc[3] * acc[3])));
        int bb   = p >> 12;
        int nloc = p & (NN - 1);
        float* cp = cpack + (size_t)bb * NN * 4 + (size_t)(nloc >> 1) * 8 + (nloc & 1);
        cp[0] = acc[0]; cp[2] = acc[1]; cp[4] = acc[2]; cp[6] = acc[3];
    }
}

// ---- fallback-only helpers (degenerate C > CAP path) ----------------------------
__device__ __forceinline__ void sort64_pair(float& v, int& m, int lane) {
    #pragma unroll
    for (int k = 2; k <= 64; k <<= 1) {
        #pragma unroll
        for (int j = k >> 1; j >= 1; j >>= 1) {
            float ov = __shfl_xor(v, j);
            int   om = __shfl_xor(m, j);
            bool keepMin = (((lane & j) == 0) == ((lane & k) == 0));
            bool less = (ov < v) || (ov == v && om < m);
            bool take = (less == keepMin);
            v = take ? ov : v;
            m = take ? om : m;
        }
    }
}
__device__ __forceinline__ void merge64(float& Lv, int& Lm, float cv, int cm, int lane) {
    float rv = __shfl_xor(cv, 63);
    int   rm = __shfl_xor(cm, 63);
    bool less = (rv < Lv) || (rv == Lv && rm < Lm);
    if (less) { Lv = rv; Lm = rm; }
    #pragma unroll
    for (int j = 32; j >= 1; j >>= 1) {
        float ov = __shfl_xor(Lv, j);
        int   om = __shfl_xor(Lm, j);
        bool lower = ((lane & j) == 0);
        bool l2 = (ov < Lv) || (ov == Lv && om < Lm);
        bool take = (l2 == lower);
        Lv = take ? ov : Lv;
        Lm = take ? om : Lm;
    }
}

// ---------------- per-query tail: selection + stage + aggregate + epilogue -------
__device__ __forceinline__ void tail_query(
    int lane, int b, int nj, int qj, int C,
    const unsigned short* __restrict__ selq,
    const float4* __restrict__ c4, const float* __restrict__ sqb,
    const float* __restrict__ feats,
    const float* __restrict__ x, const float* __restrict__ Wo,
    const float* __restrict__ bo,
    float* __restrict__ fstage, float* __restrict__ agg,
    float* __restrict__ out)
{
    const float INF = __builtin_inff();
    const float NEGINF = -INF;
    float4 cqj = c4[nj];
    float sqnj = sqb[nj];

    if (C <= CAP) {
        unsigned kd0 = 0xFFFFFFFFu, ki0 = 0xFFFFFFFFu; float dv0 = 0.f;
        if (lane < C) {
            unsigned idx = (unsigned)selq[lane];
            float4 cm = c4[idx];
            float s2 = sqb[idx];
            float dt = fmaf(cqj.x, cm.x, fmaf(cqj.y, cm.y, fmaf(cqj.z, cm.z, cqj.w * cm.w)));
            float d  = fmaxf(fmaf(-2.f, dt, s2 + sqnj), 0.f);
            dv0 = d; kd0 = __float_as_uint(d); ki0 = idx;
        }
        unsigned kd1 = 0xFFFFFFFFu, ki1 = 0xFFFFFFFFu; float dv1 = 0.f;
        if (64 + lane < C) {
            unsigned idx = (unsigned)selq[64 + lane];
            float4 cm = c4[idx];
            float s2 = sqb[idx];
            float dt = fmaf(cqj.x, cm.x, fmaf(cqj.y, cm.y, fmaf(cqj.z, cm.z, cqj.w * cm.w)));
            float d  = fmaxf(fmaf(-2.f, dt, s2 + sqnj), 0.f);
            dv1 = d; kd1 = __float_as_uint(d); ki1 = idx;
        }
        // D = exact 39th-smallest clamped d2 bits (must stay exact)
        unsigned D = 0;
        for (int bit = 30; bit >= 0; --bit) {
            unsigned t = D | (1u << bit);
            int c = (int)__popcll(__ballot(kd0 < t))
                  + (int)__popcll(__ballot(kd1 < t));
            if (c < KSEL) D = t;
        }
        int cless  = (int)__popcll(__ballot(kd0 < D))
                   + (int)__popcll(__ballot(kd1 < D));
        int tiecnt = (int)__popcll(__ballot(kd0 == D))
                   + (int)__popcll(__ballot(kd1 == D));
        int tneed = KSEL - cless;
        unsigned TI = 0xFFFFFFFFu;
        if (tiecnt > tneed) {            // rare: resolve ties by lowest index
            unsigned pi = 0;
            for (int bit = 11; bit >= 0; --bit) {
                unsigned t = pi | (1u << bit);
                int c = (int)__popcll(__ballot((kd0 == D) && (ki0 < t)))
                      + (int)__popcll(__ballot((kd1 == D) && (ki1 < t)));
                if (c < tneed) pi = t;
            }
            TI = pi;
        }
        // stage the exactly-39 selected neighbors (ballot/prefix slots, no atomics)
        bool take0 = (kd0 < D) || ((kd0 == D) && (ki0 <= TI));
        bool take1 = (kd1 < D) || ((kd1 == D) && (ki1 <= TI));
        unsigned long long tb0 = __ballot(take0);
        unsigned long long tb1 = __ballot(take1);
        unsigned base1 = (unsigned)__popcll(tb0);
        if (take0) {
            unsigned slot = (unsigned)lane_prefix(tb0);
            float wgt = __expf(-10.f * dv0);
            const float4* fr = (const float4*)(feats + ((size_t)b * NN + ki0) * PPAD);
            float4 f0 = fr[0], f1 = fr[1], f2 = fr[2], f3 = fr[3], f4 = fr[4], f5 = fr[5];
            float4* row = (float4*)(fstage + slot * PPAD);
            row[0] = make_float4(f0.x * wgt, f0.y * wgt, f0.z * wgt, f0.w * wgt);
            row[1] = make_float4(f1.x * wgt, f1.y * wgt, f1.z * wgt, f1.w * wgt);
            row[2] = make_float4(f2.x * wgt, f2.y * wgt, f2.z * wgt, f2.w * wgt);
            row[3] = make_float4(f3.x * wgt, f3.y * wgt, f3.z * wgt, f3.w * wgt);
            row[4] = make_float4(f4.x * wgt, f4.y * wgt, f4.z * wgt, f4.w * wgt);
            row[5] = make_float4(f5.x * wgt, f5.y * wgt, f5.z * wgt, f5.w * wgt);
        }
        if (take1) {
            unsigned slot = base1 + (unsigned)lane_prefix(tb1);
            float wgt = __expf(-10.f * dv1);
            const float4* fr = (const float4*)(feats + ((size_t)b * NN + ki1) * PPAD);
            float4 f0 = fr[0], f1 = fr[1], f2 = fr[2], f3 = fr[3], f4 = fr[4], f5 = fr[5];
            float4* row = (float4*)(fstage + slot * PPAD);
            row[0] = make_float4(f0.x * wgt, f0.y * wgt, f0.z * wgt, f0.w * wgt);
            row[1] = make_float4(f1.x * wgt, f1.y * wgt, f1.z * wgt, f1.w * wgt);
            row[2] = make_float4(f2.x * wgt, f2.y * wgt, f2.z * wgt, f2.w * wgt);
            row[3] = make_float4(f3.x * wgt, f3.y * wgt, f3.z * wgt, f3.w * wgt);
            row[4] = make_float4(f4.x * wgt, f4.y * wgt, f4.z * wgt, f4.w * wgt);
            row[5] = make_float4(f5.x * wgt, f5.y * wgt, f5.z * wgt, f5.w * wgt);
        }
    } else {
        // degenerate fallback: exact streaming top-64 over all 4096
        float Lv = INF; int Lm = 0x7FFFFFFF;
        for (int c = 0; c < 64; ++c) {
            int m = c * 64 + lane;
            float4 cm = c4[m];
            float s2 = sqb[m];
            float dt = fmaf(cqj.x, cm.x, fmaf(cqj.y, cm.y, fmaf(cqj.z, cm.z, cqj.w * cm.w)));
            float v  = fmaxf(fmaf(-2.f, dt, s2 + sqnj), 0.f);
            if (m == nj) v = INF;
            sort64_pair(v, m, lane);
            if (c == 0) { Lv = v; Lm = m; }
            else        merge64(Lv, Lm, v, m, lane);
        }
        if (lane < KSEL) {
            float wgt = __expf(-10.f * Lv);
            const float4* fr = (const float4*)(feats + ((size_t)b * NN + Lm) * PPAD);
            float4 f0 = fr[0], f1 = fr[1], f2 = fr[2], f3 = fr[3], f4 = fr[4], f5 = fr[5];
            float4* row = (float4*)(fstage + lane * PPAD);
            row[0] = make_float4(f0.x * wgt, f0.y * wgt, f0.z * wgt, f0.w * wgt);
            row[1] = make_float4(f1.x * wgt, f1.y * wgt, f1.z * wgt, f1.w * wgt);
            row[2] = make_float4(f2.x * wgt, f2.y * wgt, f2.z * wgt, f2.w * wgt);
            row[3] = make_float4(f3.x * wgt, f3.y * wgt, f3.z * wgt, f3.w * wgt);
            row[4] = make_float4(f4.x * wgt, f4.y * wgt, f4.z * wgt, f4.w * wgt);
            row[5] = make_float4(f5.x * wgt, f5.y * wgt, f5.z * wgt, f5.w * wgt);
        }
    }
    WSYNC();

    // ---- max / mean over 39 neighbors: 44 lanes, split-k ----
    if (lane < 2 * PP) {
        int g  = (lane >= PP) ? 1 : 0;
        int c  = lane - g * PP;
        int k0 = g ? 20 : 0;
        int k1 = g ? KSEL : 20;
        float mx = NEGINF, sm = 0.f;
        for (int k = k0; k < k1; ++k) {
            float v = fstage[k * PPAD + c];
            mx = fmaxf(mx, v);
            sm += v;
        }
        float mx2 = __shfl(mx, lane + PP);
        float sm2 = __shfl(sm, lane + PP);
        if (lane < PP) {
            agg[c]      = fmaxf(mx, mx2);
            agg[PP + c] = (sm + sm2) * (1.f / (float)KSEL);
        }
    }
    WSYNC();

    // ---- epilogue: out = tanh([x | max | mean] @ Wo + bo), fast tanh ----
    if (lane < FOUT) {
        const float* xr  = x + (size_t)qj * FIN;
        const float* woL = Wo + lane;
        float a0 = bo[lane], a1 = 0.f, a2 = 0.f, a3 = 0.f;
        #pragma unroll
        for (int f = 0; f < FIN; f += 4) {
            a0 = fmaf(xr[f + 0], woL[(f + 0) * FOUT], a0);
            a1 = fmaf(xr[f + 1], woL[(f + 1) * FOUT], a1);
            a2 = fmaf(xr[f + 2], woL[(f + 2) * FOUT], a2);
            a3 = fmaf(xr[f + 3], woL[(f + 3) * FOUT], a3);
        }
        #pragma unroll
        for (int f = 0; f < 2 * PP; f += 4) {
            a0 = fmaf(agg[f + 0], woL[(FIN + f + 0) * FOUT], a0);
            a1 = fmaf(agg[f + 1], woL[(FIN + f + 1) * FOUT], a1);
            a2 = fmaf(agg[f + 2], woL[(FIN + f + 2) * FOUT], a2);
            a3 = fmaf(agg[f + 3], woL[(FIN + f + 3) * FOUT], a3);
        }
        float acc = (a0 + a1) + (a2 + a3);
        float e = __expf(2.f * acc);
        float r = __builtin_amdgcn_rcpf(e + 1.f);
        out[(size_t)qj * FOUT + lane] = fmaf(-2.f, r, 1.f);
    }
    WSYNC();
}

// ---------------- main: one wave per FOUR queries, packed-f32 pair passes --------
__global__ __launch_bounds__(WPB * 64, 8) void gn_main(
    const float* __restrict__ x,
    const float* __restrict__ Wo, const float* __restrict__ bo,
    const float* __restrict__ coords4, const float* __restrict__ sqn,
    const float* __restrict__ cpack,
    const float* __restrict__ feats,
    float* __restrict__ out)
{
    __shared__ unsigned short sel_s[WPB * QW * CAP];     // candidate indices
    __shared__ float fstage_s[WPB * KSEL * PPAD];
    __shared__ float agg_s[WPB * 48];

    const float INF = __builtin_inff();
    const int wv    = threadIdx.x >> 6;
    const int lane  = threadIdx.x & 63;
    const int qbase = (blockIdx.x * WPB + wv) * QW;      // 4 queries, same batch
    const int b     = qbase >> 12;
    const int n0    = qbase & (NN - 1);
    unsigned short* selp = sel_s + wv * QW * CAP;
    float* fstage = fstage_s + wv * (KSEL * PPAD);
    float* agg    = agg_s + wv * 48;

    const float4* c4  = ((const float4*)coords4) + (size_t)b * NN;
    const float*  sqb = sqn + (size_t)b * NN;
    const float4* cp4 = ((const float4*)cpack) + (size_t)b * NN;   // 2 float4 per pair group
    const f32x2*  sq2 = (const f32x2*)sqb;

    // per-query constants -- individual scalars only
    float4 cq0 = c4[n0 + 0], cq1 = c4[n0 + 1], cq2 = c4[n0 + 2], cq3 = c4[n0 + 3];
    float sq0 = sqb[n0 + 0], sq1 = sqb[n0 + 1], sq2s = sqb[n0 + 2], sq3 = sqb[n0 + 3];

    const f32x2 M2 = {-2.f, -2.f};
    f32x2 qx0 = {cq0.x, cq0.x}, qy0 = {cq0.y, cq0.y}, qz0 = {cq0.z, cq0.z}, qw0 = {cq0.w, cq0.w};
    f32x2 qx1 = {cq1.x, cq1.x}, qy1 = {cq1.y, cq1.y}, qz1 = {cq1.z, cq1.z}, qw1 = {cq1.w, cq1.w};
    f32x2 qx2 = {cq2.x, cq2.x}, qy2 = {cq2.y, cq2.y}, qz2 = {cq2.z, cq2.z}, qw2 = {cq2.w, cq2.w};
    f32x2 qx3 = {cq3.x, cq3.x}, qy3 = {cq3.y, cq3.y}, qz3 = {cq3.z, cq3.z}, qw3 = {cq3.w, cq3.w};
    f32x2 sqp0 = {sq0, sq0}, sqp1 = {sq1, sq1}, sqp2 = {sq2s, sq2s}, sqp3 = {sq3, sq3};

    // ---- pass 1: packed pair distances, per-query running min (self included) ----
    // candidates per iter: m = i*128 + 2*lane + {0,1}; bit-identical math to scalar.
    f32x2 km0 = {INF, INF}, km1 = {INF, INF}, km2 = {INF, INF}, km3 = {INF, INF};
    #pragma unroll 4
    for (int i = 0; i < 32; ++i) {
        int g = i * 64 + lane;                 // pair group
        float4 a  = cp4[g * 2];                // x0,x1,y0,y1
        float4 bb = cp4[g * 2 + 1];            // z0,z1,w0,w1
        f32x2 X = {a.x, a.y}, Y = {a.z, a.w}, Z = {bb.x, bb.y}, W = {bb.z, bb.w};
        f32x2 S2 = sq2[g];
        f32x2 dt0 = __builtin_elementwise_fma(qx0, X, __builtin_elementwise_fma(qy0, Y,
                    __builtin_elementwise_fma(qz0, Z, qw0 * W)));
        f32x2 dt1 = __builtin_elementwise_fma(qx1, X, __builtin_elementwise_fma(qy1, Y,
                    __builtin_elementwise_fma(qz1, Z, qw1 * W)));
        f32x2 dt2 = __builtin_elementwise_fma(qx2, X, __builtin_elementwise_fma(qy2, Y,
                    __builtin_elementwise_fma(qz2, Z, qw2 * W)));
        f32x2 dt3 = __builtin_elementwise_fma(qx3, X, __builtin_elementwise_fma(qy3, Y,
                    __builtin_elementwise_fma(qz3, Z, qw3 * W)));
        km0 = __builtin_elementwise_min(km0, __builtin_elementwise_fma(M2, dt0, S2 + sqp0));
        km1 = __builtin_elementwise_min(km1, __builtin_elementwise_fma(M2, dt1, S2 + sqp1));
        km2 = __builtin_elementwise_min(km2, __builtin_elementwise_fma(M2, dt2, S2 + sqp2));
        km3 = __builtin_elementwise_min(km3, __builtin_elementwise_fma(M2, dt3, S2 + sqp3));
    }
    unsigned kb0 = __float_as_uint(fmaxf(fminf(km0.x, km0.y), 0.f));
    unsigned kb1 = __float_as_uint(fmaxf(fminf(km1.x, km1.y), 0.f));
    unsigned kb2 = __float_as_uint(fmaxf(fminf(km2.x, km2.y), 0.f));
    unsigned kb3 = __float_as_uint(fmaxf(fminf(km3.x, km3.y), 0.f));

    // ---- bounds: 40th-smallest lane-min per query, TRUNCATED radix (bits 30..15)
    unsigned ub0 = 0, ub1 = 0, ub2 = 0, ub3 = 0;
    for (int bit = 30; bit >= 15; --bit) {
        unsigned msk = 1u << bit;
        unsigned t0 = ub0 | msk, t1 = ub1 | msk, t2 = ub2 | msk, t3 = ub3 | msk;
        if ((int)__popcll(__ballot(kb0 < t0)) < KSEL + 1) ub0 = t0;
        if ((int)__popcll(__ballot(kb1 < t1)) < KSEL + 1) ub1 = t1;
        if ((int)__popcll(__ballot(kb2 < t2)) < KSEL + 1) ub2 = t2;
        if ((int)__popcll(__ballot(kb3 < t3)) < KSEL + 1) ub3 = t3;
    }
    float UB0 = __uint_as_float(ub0 | 0x7FFFu);
    float UB1 = __uint_as_float(ub1 | 0x7FFFu);
    float UB2 = __uint_as_float(ub2 | 0x7FFFu);
    float UB3 = __uint_as_float(ub3 | 0x7FFFu);

    // self positions: all four selves are inside ONE iteration (n0 % 4 == 0)
    const int iSelf = n0 >> 7;                 // iter index of the self pair-groups
    const int slA   = (n0 & 127) >> 1;         // lane of selves j=0 (h=0), j=1 (h=1)
    const int slB   = slA + 1;                 // lane of selves j=2 (h=0), j=3 (h=1)

    // ---- compact pass: packed pair distances, ballot/prefix slot assignment ----
    unsigned cc0 = 0, cc1 = 0, cc2 = 0, cc3 = 0;
    #pragma unroll 4
    for (int i = 0; i < 32; ++i) {
        int g = i * 64 + lane;
        int m0 = i * 128 + 2 * lane;           // even candidate, odd = m0+1
        float4 a  = cp4[g * 2];
        float4 bb = cp4[g * 2 + 1];
        f32x2 X = {a.x, a.y}, Y = {a.z, a.w}, Z = {bb.x, bb.y}, W = {bb.z, bb.w};
        f32x2 S2 = sq2[g];
        f32x2 dt0 = __builtin_elementwise_fma(qx0, X, __builtin_elementwise_fma(qy0, Y,
                    __builtin_elementwise_fma(qz0, Z, qw0 * W)));
        f32x2 dt1 = __builtin_elementwise_fma(qx1, X, __builtin_elementwise_fma(qy1, Y,
                    __builtin_elementwise_fma(qz1, Z, qw1 * W)));
        f32x2 dt2 = __builtin_elementwise_fma(qx2, X, __builtin_elementwise_fma(qy2, Y,
                    __builtin_elementwise_fma(qz2, Z, qw2 * W)));
        f32x2 dt3 = __builtin_elementwise_fma(qx3, X, __builtin_elementwise_fma(qy3, Y,
                    __builtin_elementwise_fma(qz3, Z, qw3 * W)));
        f32x2 d0 = __builtin_elementwise_fma(M2, dt0, S2 + sqp0);
        f32x2 d1 = __builtin_elementwise_fma(M2, dt1, S2 + sqp1);
        f32x2 d2 = __builtin_elementwise_fma(M2, dt2, S2 + sqp2);
        f32x2 d3 = __builtin_elementwise_fma(M2, dt3, S2 + sqp3);
        bool t00 = d0.x <= UB0, t01 = d0.y <= UB0;
        bool t10 = d1.x <= UB1, t11 = d1.y <= UB1;
        bool t20 = d2.x <= UB2, t21 = d2.y <= UB2;
        bool t30 = d3.x <= UB3, t31 = d3.y <= UB3;
        if (i == iSelf) {                       // wave-uniform, 1 of 32 iters
            t00 = t00 && (lane != slA);         // j=0: m=n0+0 (h=0, lane slA)
            t11 = t11 && (lane != slA);         // j=1: m=n0+1 (h=1, lane slA)
            t20 = t20 && (lane != slB);         // j=2: m=n0+2 (h=0, lane slB)
            t31 = t31 && (lane != slB);         // j=3: m=n0+3 (h=1, lane slB)
        }
        unsigned long long b00 = __ballot(t00), b01 = __ballot(t01);
        unsigned long long b10 = __ballot(t10), b11 = __ballot(t11);
        unsigned long long b20 = __ballot(t20), b21 = __ballot(t21);
        unsigned long long b30 = __ballot(t30), b31 = __ballot(t31);
        unsigned p00 = (unsigned)__popcll(b00);
        unsigned p10 = (unsigned)__popcll(b10);
        unsigned p20 = (unsigned)__popcll(b20);
        unsigned p30 = (unsigned)__popcll(b30);
        if (t00) { unsigned s = cc0 + (unsigned)lane_prefix(b00);
                   if (s < CAP) selp[0 * CAP + s] = (unsigned short)m0; }
        if (t01) { unsigned s = cc0 + p00 + (unsigned)lane_prefix(b01);
                   if (s < CAP) selp[0 * CAP + s] = (unsigned short)(m0 + 1); }
        if (t10) { unsigned s = cc1 + (unsigned)lane_prefix(b10);
                   if (s < CAP) selp[1 * CAP + s] = (unsigned short)m0; }
        if (t11) { unsigned s = cc1 + p10 + (unsigned)lane_prefix(b11);
                   if (s < CAP) selp[1 * CAP + s] = (unsigned short)(m0 + 1); }
        if (t20) { unsigned s = cc2 + (unsigned)lane_prefix(b20);
                   if (s < CAP) selp[2 * CAP + s] = (unsigned short)m0; }
        if (t21) { unsigned s = cc2 + p20 + (unsigned)lane_prefix(b21);
                   if (s < CAP) selp[2 * CAP + s] = (unsigned short)(m0 + 1); }
        if (t30) { unsigned s = cc3 + (unsigned)lane_prefix(b30);
                   if (s < CAP) selp[3 * CAP + s] = (unsigned short)m0; }
        if (t31) { unsigned s = cc3 + p30 + (unsigned)lane_prefix(b31);
                   if (s < CAP) selp[3 * CAP + s] = (unsigned short)(m0 + 1); }
        cc0 += p00 + (unsigned)__popcll(b01);
        cc1 += p10 + (unsigned)__popcll(b11);
        cc2 += p20 + (unsigned)__popcll(b21);
        cc3 += p30 + (unsigned)__popcll(b31);
    }
    WSYNC();

    // ---- four explicit tail calls (no runtime-indexed private state) ----
    tail_query(lane, b, n0 + 0, qbase + 0, (int)cc0, selp + 0 * CAP,
               c4, sqb, feats, x, Wo, bo, fstage, agg, out);
    tail_query(lane, b, n0 + 1, qbase + 1, (int)cc1, selp + 1 * CAP,
               c4, sqb, feats, x, Wo, bo, fstage, agg, out);
    tail_query(lane, b, n0 + 2, qbase + 2, (int)cc2, selp + 2 * CAP,
               c4, sqb, feats, x, Wo, bo, fstage, agg, out);
    tail_query(lane, b, n0 + 3, qbase + 3, (int)cc3, selp + 3 * CAP,
               c4, sqb, feats, x, Wo, bo, fstage, agg, out);
}

extern "C" void kernel_launch(void* const* d_in, const int* in_sizes, int n_in,
                              void* d_out, int out_size, void* d_ws, size_t ws_size,
                              hipStream_t stream) {
    const float* x  = (const float*)d_in[0];
    const float* Wf = (const float*)d_in[1];
    const float* bf = (const float*)d_in[2];
    const float* Ws = (const float*)d_in[3];
    const float* bs = (const float*)d_in[4];
    const float* Wo = (const float*)d_in[5];
    const float* bo = (const float*)d_in[6];
    float* outp = (float*)d_out;

    float* ws      = (float*)d_ws;
    float* coords4 = ws;                                // 32768*4  = 131072 floats
    float* feats   = ws + 131072;                       // 32768*24 = 786432 floats
    float* sqn     = ws + 131072 + 786432;              // 32768 floats
    float* cpack   = ws + 131072 + 786432 + 32768;      // 32768*4  = 131072 floats

    gn_pre<<<(32768 * 4) / 256, 256, 0, stream>>>(x, Wf, bf, Ws, bs, coords4, feats, sqn, cpack);
    gn_main<<<32768 / (WPB * QW), WPB * 64, 0, stream>>>(x, Wo, bo, coords4, sqn, cpack, feats, outp);
}

// Round 4
// 206.457 us; speedup vs baseline: 2.3489x; 2.3489x over previous
//
#include <hip/hip_runtime.h>
#include <cmath>

#define NN    4096
#define FIN   32
#define KSEL  39      // neighbors kept (top-40 minus self)
#define PP    22
#define PPAD  24
#define FOUT  48
#define WPB   2       // waves per block
#define QW    4       // queries per wave
#define CAP   128     // candidate cap per query (fallback if exceeded)
#define WCOLS 32      // combined weight columns: [Wf(22) | pad(2) | Ws(4) | pad(4)]

#define WSYNC() asm volatile("s_waitcnt lgkmcnt(0)" ::: "memory")

__device__ __forceinline__ int lane_prefix(unsigned long long m) {
    return __builtin_amdgcn_mbcnt_hi((unsigned)(m >> 32),
           __builtin_amdgcn_mbcnt_lo((unsigned)m, 0));
}
// order-preserving float<->uint maps (total order, handles negatives)
__device__ __forceinline__ unsigned ford(float f) {
    int u = __float_as_int(f);
    return (u >= 0) ? ((unsigned)u | 0x80000000u) : ~(unsigned)u;
}
__device__ __forceinline__ float funord(unsigned k) {
    unsigned v = (k & 0x80000000u) ? (k & 0x7FFFFFFFu) : ~k;
    return __uint_as_float(v);
}

// ---------------- precompute: 4 threads per point, LDS-staged weights ------------
__global__ __launch_bounds__(256) void gn_pre(
    const float* __restrict__ x,
    const float* __restrict__ Wf, const float* __restrict__ bf,
    const float* __restrict__ Ws, const float* __restrict__ bs,
    float* __restrict__ coords4, float* __restrict__ feats,
    float* __restrict__ sqn)
{
    __shared__ __align__(16) float sW[FIN * WCOLS];
    __shared__ float sB[WCOLS];

    int t = threadIdx.x;
    for (int idx = t; idx < FIN * WCOLS; idx += 256) {
        int i = idx >> 5, c = idx & 31;
        float v = 0.f;
        if (c < PP) v = Wf[i * PP + c];
        else if (c >= 24 && c < 28) v = Ws[i * 4 + (c - 24)];
        sW[idx] = v;
    }
    if (t < WCOLS) {
        float v = 0.f;
        if (t < PP) v = bf[t];
        else if (t >= 24 && t < 28) v = bs[t - 24];
        sB[t] = v;
    }
    __syncthreads();

    int gid = blockIdx.x * 256 + t;
    int p = gid >> 2;          // point
    int h = gid & 3;           // column strip
    int c0 = h * 8;

    const float4* xr4 = (const float4*)(x + (size_t)p * FIN);
    float acc[8];
    #pragma unroll
    for (int k = 0; k < 8; ++k) acc[k] = sB[c0 + k];

    #pragma unroll
    for (int i = 0; i < 8; ++i) {
        float4 xt = xr4[i];
        const float* w0 = sW + (4 * i + 0) * WCOLS + c0;
        const float* w1 = sW + (4 * i + 1) * WCOLS + c0;
        const float* w2 = sW + (4 * i + 2) * WCOLS + c0;
        const float* w3 = sW + (4 * i + 3) * WCOLS + c0;
        #pragma unroll
        for (int k = 0; k < 8; ++k) acc[k] = fmaf(xt.x, w0[k], acc[k]);
        #pragma unroll
        for (int k = 0; k < 8; ++k) acc[k] = fmaf(xt.y, w1[k], acc[k]);
        #pragma unroll
        for (int k = 0; k < 8; ++k) acc[k] = fmaf(xt.z, w2[k], acc[k]);
        #pragma unroll
        for (int k = 0; k < 8; ++k) acc[k] = fmaf(xt.w, w3[k], acc[k]);
    }

    if (h < 3) {
        float4* fw = (float4*)(feats + (size_t)p * PPAD + c0);
        fw[0] = make_float4(acc[0], acc[1], acc[2], acc[3]);
        fw[1] = make_float4(acc[4], acc[5], acc[6], acc[7]);   // h=2: cols 22,23 exact 0
    } else {
        ((float4*)coords4)[p] = make_float4(acc[0], acc[1], acc[2], acc[3]);
        sqn[p] = fmaf(acc[0], acc[0], fmaf(acc[1], acc[1],
                 fmaf(acc[2], acc[2], acc[3] * acc[3])));
    }
}

// ---- fallback-only helpers (degenerate C > CAP path) ----------------------------
__device__ __forceinline__ void sort64_pair(float& v, int& m, int lane) {
    #pragma unroll
    for (int k = 2; k <= 64; k <<= 1) {
        #pragma unroll
        for (int j = k >> 1; j >= 1; j >>= 1) {
            float ov = __shfl_xor(v, j);
            int   om = __shfl_xor(m, j);
            bool keepMin = (((lane & j) == 0) == ((lane & k) == 0));
            bool less = (ov < v) || (ov == v && om < m);
            bool take = (less == keepMin);
            v = take ? ov : v;
            m = take ? om : m;
        }
    }
}
__device__ __forceinline__ void merge64(float& Lv, int& Lm, float cv, int cm, int lane) {
    float rv = __shfl_xor(cv, 63);
    int   rm = __shfl_xor(cm, 63);
    bool less = (rv < Lv) || (rv == Lv && rm < Lm);
    if (less) { Lv = rv; Lm = rm; }
    #pragma unroll
    for (int j = 32; j >= 1; j >>= 1) {
        float ov = __shfl_xor(Lv, j);
        int   om = __shfl_xor(Lm, j);
        bool lower = ((lane & j) == 0);
        bool l2 = (ov < Lv) || (ov == Lv && om < Lm);
        bool take = (l2 == lower);
        Lv = take ? ov : Lv;
        Lm = take ? om : Lm;
    }
}

// ---------------- per-query finish: ties + staging + aggregate + epilogue --------
// D (exact 39th-smallest clamped-d2 bits) is computed in the FUSED radix upstream.
__device__ __forceinline__ void tail_finish(
    int lane, int b, int nj, int qj, int C,
    unsigned kd0, unsigned ki0, unsigned kd1, unsigned ki1, unsigned D,
    float4 cqj, float sqnj,
    const float4* __restrict__ c4, const float* __restrict__ sqb,
    const float* __restrict__ feats,
    const float* __restrict__ x, const float* __restrict__ Wo,
    const float* __restrict__ bo,
    float* __restrict__ fstage, float* __restrict__ agg,
    float* __restrict__ out)
{
    const float INF = __builtin_inff();
    const float NEGINF = -INF;

    if (C <= CAP) {
        int cless  = (int)__popcll(__ballot(kd0 < D))
                   + (int)__popcll(__ballot(kd1 < D));
        int tiecnt = (int)__popcll(__ballot(kd0 == D))
                   + (int)__popcll(__ballot(kd1 == D));
        int tneed = KSEL - cless;
        unsigned TI = 0xFFFFFFFFu;
        if (tiecnt > tneed) {            // rare: resolve ties by lowest index
            unsigned pi = 0;
            for (int bit = 11; bit >= 0; --bit) {
                unsigned t = pi | (1u << bit);
                int c = (int)__popcll(__ballot((kd0 == D) && (ki0 < t)))
                      + (int)__popcll(__ballot((kd1 == D) && (ki1 < t)));
                if (c < tneed) pi = t;
            }
            TI = pi;
        }
        bool take0 = (kd0 < D) || ((kd0 == D) && (ki0 <= TI));
        bool take1 = (kd1 < D) || ((kd1 == D) && (ki1 <= TI));
        unsigned long long tb0 = __ballot(take0);
        unsigned long long tb1 = __ballot(take1);
        unsigned base1 = (unsigned)__popcll(tb0);
        if (take0) {
            unsigned slot = (unsigned)lane_prefix(tb0);
            float wgt = __expf(-10.f * __uint_as_float(kd0));
            const float4* fr = (const float4*)(feats + ((size_t)b * NN + ki0) * PPAD);
            float4 f0 = fr[0], f1 = fr[1], f2 = fr[2], f3 = fr[3], f4 = fr[4], f5 = fr[5];
            float4* row = (float4*)(fstage + slot * PPAD);
            row[0] = make_float4(f0.x * wgt, f0.y * wgt, f0.z * wgt, f0.w * wgt);
            row[1] = make_float4(f1.x * wgt, f1.y * wgt, f1.z * wgt, f1.w * wgt);
            row[2] = make_float4(f2.x * wgt, f2.y * wgt, f2.z * wgt, f2.w * wgt);
            row[3] = make_float4(f3.x * wgt, f3.y * wgt, f3.z * wgt, f3.w * wgt);
            row[4] = make_float4(f4.x * wgt, f4.y * wgt, f4.z * wgt, f4.w * wgt);
            row[5] = make_float4(f5.x * wgt, f5.y * wgt, f5.z * wgt, f5.w * wgt);
        }
        if (take1) {
            unsigned slot = base1 + (unsigned)lane_prefix(tb1);
            float wgt = __expf(-10.f * __uint_as_float(kd1));
            const float4* fr = (const float4*)(feats + ((size_t)b * NN + ki1) * PPAD);
            float4 f0 = fr[0], f1 = fr[1], f2 = fr[2], f3 = fr[3], f4 = fr[4], f5 = fr[5];
            float4* row = (float4*)(fstage + slot * PPAD);
            row[0] = make_float4(f0.x * wgt, f0.y * wgt, f0.z * wgt, f0.w * wgt);
            row[1] = make_float4(f1.x * wgt, f1.y * wgt, f1.z * wgt, f1.w * wgt);
            row[2] = make_float4(f2.x * wgt, f2.y * wgt, f2.z * wgt, f2.w * wgt);
            row[3] = make_float4(f3.x * wgt, f3.y * wgt, f3.z * wgt, f3.w * wgt);
            row[4] = make_float4(f4.x * wgt, f4.y * wgt, f4.z * wgt, f4.w * wgt);
            row[5] = make_float4(f5.x * wgt, f5.y * wgt, f5.z * wgt, f5.w * wgt);
        }
    } else {
        // degenerate fallback: exact streaming top-64 over all 4096
        float Lv = INF; int Lm = 0x7FFFFFFF;
        for (int c = 0; c < 64; ++c) {
            int m = c * 64 + lane;
            float4 cm = c4[m];
            float s2 = sqb[m];
            float dt = fmaf(cqj.x, cm.x, fmaf(cqj.y, cm.y, fmaf(cqj.z, cm.z, cqj.w * cm.w)));
            float v  = fmaxf(fmaf(-2.f, dt, s2 + sqnj), 0.f);
            if (m == nj) v = INF;
            sort64_pair(v, m, lane);
            if (c == 0) { Lv = v; Lm = m; }
            else        merge64(Lv, Lm, v, m, lane);
        }
        if (lane < KSEL) {
            float wgt = __expf(-10.f * Lv);
            const float4* fr = (const float4*)(feats + ((size_t)b * NN + Lm) * PPAD);
            float4 f0 = fr[0], f1 = fr[1], f2 = fr[2], f3 = fr[3], f4 = fr[4], f5 = fr[5];
            float4* row = (float4*)(fstage + lane * PPAD);
            row[0] = make_float4(f0.x * wgt, f0.y * wgt, f0.z * wgt, f0.w * wgt);
            row[1] = make_float4(f1.x * wgt, f1.y * wgt, f1.z * wgt, f1.w * wgt);
            row[2] = make_float4(f2.x * wgt, f2.y * wgt, f2.z * wgt, f2.w * wgt);
            row[3] = make_float4(f3.x * wgt, f3.y * wgt, f3.z * wgt, f3.w * wgt);
            row[4] = make_float4(f4.x * wgt, f4.y * wgt, f4.z * wgt, f4.w * wgt);
            row[5] = make_float4(f5.x * wgt, f5.y * wgt, f5.z * wgt, f5.w * wgt);
        }
    }
    WSYNC();

    // ---- max / mean over 39 neighbors: 44 lanes, split-k ----
    if (lane < 2 * PP) {
        int g  = (lane >= PP) ? 1 : 0;
        int c  = lane - g * PP;
        int k0 = g ? 20 : 0;
        int k1 = g ? KSEL : 20;
        float mx = NEGINF, sm = 0.f;
        for (int k = k0; k < k1; ++k) {
            float v = fstage[k * PPAD + c];
            mx = fmaxf(mx, v);
            sm += v;
        }
        float mx2 = __shfl(mx, lane + PP);
        float sm2 = __shfl(sm, lane + PP);
        if (lane < PP) {
            agg[c]      = fmaxf(mx, mx2);
            agg[PP + c] = (sm + sm2) * (1.f / (float)KSEL);
        }
    }
    WSYNC();

    // ---- epilogue: out = tanh([x | max | mean] @ Wo + bo), fast tanh ----
    if (lane < FOUT) {
        const float* xr  = x + (size_t)qj * FIN;
        const float* woL = Wo + lane;
        float a0 = bo[lane], a1 = 0.f, a2 = 0.f, a3 = 0.f;
        #pragma unroll
        for (int f = 0; f < FIN; f += 4) {
            a0 = fmaf(xr[f + 0], woL[(f + 0) * FOUT], a0);
            a1 = fmaf(xr[f + 1], woL[(f + 1) * FOUT], a1);
            a2 = fmaf(xr[f + 2], woL[(f + 2) * FOUT], a2);
            a3 = fmaf(xr[f + 3], woL[(f + 3) * FOUT], a3);
        }
        #pragma unroll
        for (int f = 0; f < 2 * PP; f += 4) {
            a0 = fmaf(agg[f + 0], woL[(FIN + f + 0) * FOUT], a0);
            a1 = fmaf(agg[f + 1], woL[(FIN + f + 1) * FOUT], a1);
            a2 = fmaf(agg[f + 2], woL[(FIN + f + 2) * FOUT], a2);
            a3 = fmaf(agg[f + 3], woL[(FIN + f + 3) * FOUT], a3);
        }
        float acc = (a0 + a1) + (a2 + a3);
        float e = __expf(2.f * acc);
        float r = __builtin_amdgcn_rcpf(e + 1.f);
        out[(size_t)qj * FOUT + lane] = fmaf(-2.f, r, 1.f);
    }
    WSYNC();
}

// ---------------- main: one wave per FOUR queries --------------------------------
__global__ __launch_bounds__(WPB * 64, 4) void gn_main(
    const float* __restrict__ x,
    const float* __restrict__ Wo, const float* __restrict__ bo,
    const float* __restrict__ coords4, const float* __restrict__ sqn,
    const float* __restrict__ feats,
    float* __restrict__ out)
{
    __shared__ unsigned short sel_s[WPB * QW * CAP];     // candidate indices
    __shared__ float fstage_s[WPB * KSEL * PPAD];
    __shared__ float agg_s[WPB * 48];

    const float INF = __builtin_inff();
    const int wv    = threadIdx.x >> 6;
    const int lane  = threadIdx.x & 63;
    const int qbase = (blockIdx.x * WPB + wv) * QW;      // 4 queries, same batch
    const int b     = qbase >> 12;
    const int n0    = qbase & (NN - 1);
    unsigned short* selp = sel_s + wv * QW * CAP;
    float* fstage = fstage_s + wv * (KSEL * PPAD);
    float* agg    = agg_s + wv * 48;

    const float4* c4  = ((const float4*)coords4) + (size_t)b * NN;
    const float*  sqb = sqn + (size_t)b * NN;

    // per-query constants
    float4 cq0 = c4[n0 + 0], cq1 = c4[n0 + 1], cq2 = c4[n0 + 2], cq3 = c4[n0 + 3];
    float sq0 = sqb[n0 + 0], sq1 = sqb[n0 + 1], sq2 = sqb[n0 + 2], sq3 = sqb[n0 + 3];

    // hoisted -2*q components: e = s2 - 2*dot = fma chain, NO per-iter adds.
    // Selection in e-domain (e = d - sq_j, monotone shift) -- superset preserved;
    // the tail re-ranks with the exact original formula, so output is unchanged.
    float m2x0 = -2.f * cq0.x, m2y0 = -2.f * cq0.y, m2z0 = -2.f * cq0.z, m2w0 = -2.f * cq0.w;
    float m2x1 = -2.f * cq1.x, m2y1 = -2.f * cq1.y, m2z1 = -2.f * cq1.z, m2w1 = -2.f * cq1.w;
    float m2x2 = -2.f * cq2.x, m2y2 = -2.f * cq2.y, m2z2 = -2.f * cq2.z, m2w2 = -2.f * cq2.w;
    float m2x3 = -2.f * cq3.x, m2y3 = -2.f * cq3.y, m2z3 = -2.f * cq3.z, m2w3 = -2.f * cq3.w;

    // ---- pass 1: per-query running min of e (self included) ----
    float km0 = INF, km1 = INF, km2 = INF, km3 = INF;
    #pragma unroll 4
    for (int i = 0; i < 64; ++i) {
        float4 cm = c4[i * 64 + lane];
        float s2  = sqb[i * 64 + lane];
        float e0 = fmaf(m2x0, cm.x, fmaf(m2y0, cm.y, fmaf(m2z0, cm.z, fmaf(m2w0, cm.w, s2))));
        float e1 = fmaf(m2x1, cm.x, fmaf(m2y1, cm.y, fmaf(m2z1, cm.z, fmaf(m2w1, cm.w, s2))));
        float e2 = fmaf(m2x2, cm.x, fmaf(m2y2, cm.y, fmaf(m2z2, cm.z, fmaf(m2w2, cm.w, s2))));
        float e3 = fmaf(m2x3, cm.x, fmaf(m2y3, cm.y, fmaf(m2z3, cm.z, fmaf(m2w3, cm.w, s2))));
        km0 = fminf(km0, e0);
        km1 = fminf(km1, e1);
        km2 = fminf(km2, e2);
        km3 = fminf(km3, e3);
    }
    // order-preserving uint keys (e can be negative)
    unsigned kb0 = ford(km0), kb1 = ford(km1), kb2 = ford(km2), kb3 = ford(km3);

    // ---- bound: 40th-smallest lane-min key, TRUNCATED radix (bits 31..15),
    //      widen low 15 bits -> guaranteed >= exact 40th distance. Exact superset.
    unsigned ub0 = 0, ub1 = 0, ub2 = 0, ub3 = 0;
    for (int bit = 31; bit >= 15; --bit) {
        unsigned msk = 1u << bit;
        unsigned t0 = ub0 | msk, t1 = ub1 | msk, t2 = ub2 | msk, t3 = ub3 | msk;
        if ((int)__popcll(__ballot(kb0 < t0)) < KSEL + 1) ub0 = t0;
        if ((int)__popcll(__ballot(kb1 < t1)) < KSEL + 1) ub1 = t1;
        if ((int)__popcll(__ballot(kb2 < t2)) < KSEL + 1) ub2 = t2;
        if ((int)__popcll(__ballot(kb3 < t3)) < KSEL + 1) ub3 = t3;
    }
    float UBe0 = funord(ub0 | 0x7FFFu);
    float UBe1 = funord(ub1 | 0x7FFFu);
    float UBe2 = funord(ub2 | 0x7FFFu);
    float UBe3 = funord(ub3 | 0x7FFFu);

    // selves all sit in iteration iSelf at lanes l0..l0+3 (n0 % 4 == 0)
    const int iSelf = n0 >> 6;
    const int l0    = n0 & 63;

    // ---- compact pass: ballot/prefix slot assignment (no LDS atomics) ----
    unsigned cc0 = 0, cc1 = 0, cc2 = 0, cc3 = 0;
    #pragma unroll 4
    for (int i = 0; i < 64; ++i) {
        int m = i * 64 + lane;
        float4 cm = c4[m];
        float s2  = sqb[m];
        float e0 = fmaf(m2x0, cm.x, fmaf(m2y0, cm.y, fmaf(m2z0, cm.z, fmaf(m2w0, cm.w, s2))));
        float e1 = fmaf(m2x1, cm.x, fmaf(m2y1, cm.y, fmaf(m2z1, cm.z, fmaf(m2w1, cm.w, s2))));
        float e2 = fmaf(m2x2, cm.x, fmaf(m2y2, cm.y, fmaf(m2z2, cm.z, fmaf(m2w2, cm.w, s2))));
        float e3 = fmaf(m2x3, cm.x, fmaf(m2y3, cm.y, fmaf(m2z3, cm.z, fmaf(m2w3, cm.w, s2))));
        bool t0 = (e0 <= UBe0);
        bool t1 = (e1 <= UBe1);
        bool t2 = (e2 <= UBe2);
        bool t3 = (e3 <= UBe3);
        if (i == iSelf) {                      // wave-uniform, 1 of 64 iters
            t0 = t0 && (lane != l0 + 0);
            t1 = t1 && (lane != l0 + 1);
            t2 = t2 && (lane != l0 + 2);
            t3 = t3 && (lane != l0 + 3);
        }
        unsigned long long b0 = __ballot(t0);
        unsigned long long b1 = __ballot(t1);
        unsigned long long b2 = __ballot(t2);
        unsigned long long b3 = __ballot(t3);
        if (t0) {
            unsigned s = cc0 + (unsigned)lane_prefix(b0);
            if (s < CAP) selp[0 * CAP + s] = (unsigned short)m;
        }
        if (t1) {
            unsigned s = cc1 + (unsigned)lane_prefix(b1);
            if (s < CAP) selp[1 * CAP + s] = (unsigned short)m;
        }
        if (t2) {
            unsigned s = cc2 + (unsigned)lane_prefix(b2);
            if (s < CAP) selp[2 * CAP + s] = (unsigned short)m;
        }
        if (t3) {
            unsigned s = cc3 + (unsigned)lane_prefix(b3);
            if (s < CAP) selp[3 * CAP + s] = (unsigned short)m;
        }
        cc0 += (unsigned)__popcll(b0);
        cc1 += (unsigned)__popcll(b1);
        cc2 += (unsigned)__popcll(b2);
        cc3 += (unsigned)__popcll(b3);
    }
    WSYNC();

    // ---- FUSED candidate ranking: exact d for all 4 queries' slots, then the
    //      four 31-bit D-radix chains interleaved (latency-hidden).
    int C0 = (int)cc0, C1 = (int)cc1, C2 = (int)cc2, C3 = (int)cc3;
    int Cg0 = (C0 <= CAP) ? C0 : 0;
    int Cg1 = (C1 <= CAP) ? C1 : 0;
    int Cg2 = (C2 <= CAP) ? C2 : 0;
    int Cg3 = (C3 <= CAP) ? C3 : 0;

    unsigned kd00 = 0xFFFFFFFFu, ki00 = 0xFFFFFFFFu;
    if (lane < Cg0) {
        unsigned idx = (unsigned)selp[0 * CAP + lane];
        float4 cm = c4[idx]; float s2 = sqb[idx];
        float dt = fmaf(cq0.x, cm.x, fmaf(cq0.y, cm.y, fmaf(cq0.z, cm.z, cq0.w * cm.w)));
        float d  = fmaxf(fmaf(-2.f, dt, s2 + sq0), 0.f);
        kd00 = __float_as_uint(d); ki00 = idx;
    }
    unsigned kd01 = 0xFFFFFFFFu, ki01 = 0xFFFFFFFFu;
    if (64 + lane < Cg0) {
        unsigned idx = (unsigned)selp[0 * CAP + 64 + lane];
        float4 cm = c4[idx]; float s2 = sqb[idx];
        float dt = fmaf(cq0.x, cm.x, fmaf(cq0.y, cm.y, fmaf(cq0.z, cm.z, cq0.w * cm.w)));
        float d  = fmaxf(fmaf(-2.f, dt, s2 + sq0), 0.f);
        kd01 = __float_as_uint(d); ki01 = idx;
    }
    unsigned kd10 = 0xFFFFFFFFu, ki10 = 0xFFFFFFFFu;
    if (lane < Cg1) {
        unsigned idx = (unsigned)selp[1 * CAP + lane];
        float4 cm = c4[idx]; float s2 = sqb[idx];
        float dt = fmaf(cq1.x, cm.x, fmaf(cq1.y, cm.y, fmaf(cq1.z, cm.z, cq1.w * cm.w)));
        float d  = fmaxf(fmaf(-2.f, dt, s2 + sq1), 0.f);
        kd10 = __float_as_uint(d); ki10 = idx;
    }
    unsigned kd11 = 0xFFFFFFFFu, ki11 = 0xFFFFFFFFu;
    if (64 + lane < Cg1) {
        unsigned idx = (unsigned)selp[1 * CAP + 64 + lane];
        float4 cm = c4[idx]; float s2 = sqb[idx];
        float dt = fmaf(cq1.x, cm.x, fmaf(cq1.y, cm.y, fmaf(cq1.z, cm.z, cq1.w * cm.w)));
        float d  = fmaxf(fmaf(-2.f, dt, s2 + sq1), 0.f);
        kd11 = __float_as_uint(d); ki11 = idx;
    }
    unsigned kd20 = 0xFFFFFFFFu, ki20 = 0xFFFFFFFFu;
    if (lane < Cg2) {
        unsigned idx = (unsigned)selp[2 * CAP + lane];
        float4 cm = c4[idx]; float s2 = sqb[idx];
        float dt = fmaf(cq2.x, cm.x, fmaf(cq2.y, cm.y, fmaf(cq2.z, cm.z, cq2.w * cm.w)));
        float d  = fmaxf(fmaf(-2.f, dt, s2 + sq2), 0.f);
        kd20 = __float_as_uint(d); ki20 = idx;
    }
    unsigned kd21 = 0xFFFFFFFFu, ki21 = 0xFFFFFFFFu;
    if (64 + lane < Cg2) {
        unsigned idx = (unsigned)selp[2 * CAP + 64 + lane];
        float4 cm = c4[idx]; float s2 = sqb[idx];
        float dt = fmaf(cq2.x, cm.x, fmaf(cq2.y, cm.y, fmaf(cq2.z, cm.z, cq2.w * cm.w)));
        float d  = fmaxf(fmaf(-2.f, dt, s2 + sq2), 0.f);
        kd21 = __float_as_uint(d); ki21 = idx;
    }
    unsigned kd30 = 0xFFFFFFFFu, ki30 = 0xFFFFFFFFu;
    if (lane < Cg3) {
        unsigned idx = (unsigned)selp[3 * CAP + lane];
        float4 cm = c4[idx]; float s2 = sqb[idx];
        float dt = fmaf(cq3.x, cm.x, fmaf(cq3.y, cm.y, fmaf(cq3.z, cm.z, cq3.w * cm.w)));
        float d  = fmaxf(fmaf(-2.f, dt, s2 + sq3), 0.f);
        kd30 = __float_as_uint(d); ki30 = idx;
    }
    unsigned kd31 = 0xFFFFFFFFu, ki31 = 0xFFFFFFFFu;
    if (64 + lane < Cg3) {
        unsigned idx = (unsigned)selp[3 * CAP + 64 + lane];
        float4 cm = c4[idx]; float s2 = sqb[idx];
        float dt = fmaf(cq3.x, cm.x, fmaf(cq3.y, cm.y, fmaf(cq3.z, cm.z, cq3.w * cm.w)));
        float d  = fmaxf(fmaf(-2.f, dt, s2 + sq3), 0.f);
        kd31 = __float_as_uint(d); ki31 = idx;
    }

    // fused exact D-radix: 4 independent chains per bit (must stay exact)
    unsigned D0 = 0, D1 = 0, D2 = 0, D3 = 0;
    for (int bit = 30; bit >= 0; --bit) {
        unsigned msk = 1u << bit;
        unsigned t0 = D0 | msk, t1 = D1 | msk, t2 = D2 | msk, t3 = D3 | msk;
        int c0 = (int)__popcll(__ballot(kd00 < t0)) + (int)__popcll(__ballot(kd01 < t0));
        int c1 = (int)__popcll(__ballot(kd10 < t1)) + (int)__popcll(__ballot(kd11 < t1));
        int c2 = (int)__popcll(__ballot(kd20 < t2)) + (int)__popcll(__ballot(kd21 < t2));
        int c3 = (int)__popcll(__ballot(kd30 < t3)) + (int)__popcll(__ballot(kd31 < t3));
        if (c0 < KSEL) D0 = t0;
        if (c1 < KSEL) D1 = t1;
        if (c2 < KSEL) D2 = t2;
        if (c3 < KSEL) D3 = t3;
    }

    // ---- four per-query finishes (staging/aggregate/epilogue, unchanged) ----
    tail_finish(lane, b, n0 + 0, qbase + 0, C0, kd00, ki00, kd01, ki01, D0,
                cq0, sq0, c4, sqb, feats, x, Wo, bo, fstage, agg, out);
    tail_finish(lane, b, n0 + 1, qbase + 1, C1, kd10, ki10, kd11, ki11, D1,
                cq1, sq1, c4, sqb, feats, x, Wo, bo, fstage, agg, out);
    tail_finish(lane, b, n0 + 2, qbase + 2, C2, kd20, ki20, kd21, ki21, D2,
                cq2, sq2, c4, sqb, feats, x, Wo, bo, fstage, agg, out);
    tail_finish(lane, b, n0 + 3, qbase + 3, C3, kd30, ki30, kd31, ki31, D3,
                cq3, sq3, c4, sqb, feats, x, Wo, bo, fstage, agg, out);
}

extern "C" void kernel_launch(void* const* d_in, const int* in_sizes, int n_in,
                              void* d_out, int out_size, void* d_ws, size_t ws_size,
                              hipStream_t stream) {
    const float* x  = (const float*)d_in[0];
    const float* Wf = (const float*)d_in[1];
    const float* bf = (const float*)d_in[2];
    const float* Ws = (const float*)d_in[3];
    const float* bs = (const float*)d_in[4];
    const float* Wo = (const float*)d_in[5];
    const float* bo = (const float*)d_in[6];
    float* outp = (float*)d_out;

    float* ws      = (float*)d_ws;
    float* coords4 = ws;                      // 32768*4  = 131072 floats
    float* feats   = ws + 131072;             // 32768*24 = 786432 floats
    float* sqn     = ws + 131072 + 786432;    // 32768 floats

    gn_pre<<<(32768 * 4) / 256, 256, 0, stream>>>(x, Wf, bf, Ws, bs, coords4, feats, sqn);
    gn_main<<<32768 / (WPB * QW), WPB * 64, 0, stream>>>(x, Wo, bo, coords4, sqn, feats, outp);
}

// Round 5
// 188.975 us; speedup vs baseline: 2.5662x; 1.0925x over previous
//
#include <hip/hip_runtime.h>
#include <cmath>

#define NN    4096
#define FIN   32
#define KSEL  39      // neighbors kept (top-40 minus self)
#define PP    22
#define PPAD  24
#define FOUT  48
#define WPB   2       // waves per block
#define QW    4       // queries per wave
#define CAP   128     // candidate cap per query (fallback if exceeded)
#define WCOLS 32      // combined weight columns: [Wf(22) | pad(2) | Ws(4) | pad(4)]

#define WSYNC() asm volatile("s_waitcnt lgkmcnt(0)" ::: "memory")

__device__ __forceinline__ int lane_prefix(unsigned long long m) {
    return __builtin_amdgcn_mbcnt_hi((unsigned)(m >> 32),
           __builtin_amdgcn_mbcnt_lo((unsigned)m, 0));
}
// order-preserving float->uint map (total order, handles negatives)
__device__ __forceinline__ unsigned ford(float f) {
    int u = __float_as_int(f);
    return (u >= 0) ? ((unsigned)u | 0x80000000u) : ~(unsigned)u;
}
__device__ __forceinline__ float funord(unsigned k) {
    unsigned v = (k & 0x80000000u) ? (k & 0x7FFFFFFFu) : ~k;
    return __uint_as_float(v);
}

// ---------------- precompute: 4 threads per point, LDS-staged weights ------------
__global__ __launch_bounds__(256) void gn_pre(
    const float* __restrict__ x,
    const float* __restrict__ Wf, const float* __restrict__ bf,
    const float* __restrict__ Ws, const float* __restrict__ bs,
    float* __restrict__ coords4, float* __restrict__ feats,
    float* __restrict__ sqn)
{
    __shared__ __align__(16) float sW[FIN * WCOLS];
    __shared__ float sB[WCOLS];

    int t = threadIdx.x;
    for (int idx = t; idx < FIN * WCOLS; idx += 256) {
        int i = idx >> 5, c = idx & 31;
        float v = 0.f;
        if (c < PP) v = Wf[i * PP + c];
        else if (c >= 24 && c < 28) v = Ws[i * 4 + (c - 24)];
        sW[idx] = v;
    }
    if (t < WCOLS) {
        float v = 0.f;
        if (t < PP) v = bf[t];
        else if (t >= 24 && t < 28) v = bs[t - 24];
        sB[t] = v;
    }
    __syncthreads();

    int gid = blockIdx.x * 256 + t;
    int p = gid >> 2;          // point
    int h = gid & 3;           // column strip
    int c0 = h * 8;

    const float4* xr4 = (const float4*)(x + (size_t)p * FIN);
    float acc[8];
    #pragma unroll
    for (int k = 0; k < 8; ++k) acc[k] = sB[c0 + k];

    #pragma unroll
    for (int i = 0; i < 8; ++i) {
        float4 xt = xr4[i];
        const float* w0 = sW + (4 * i + 0) * WCOLS + c0;
        const float* w1 = sW + (4 * i + 1) * WCOLS + c0;
        const float* w2 = sW + (4 * i + 2) * WCOLS + c0;
        const float* w3 = sW + (4 * i + 3) * WCOLS + c0;
        #pragma unroll
        for (int k = 0; k < 8; ++k) acc[k] = fmaf(xt.x, w0[k], acc[k]);
        #pragma unroll
        for (int k = 0; k < 8; ++k) acc[k] = fmaf(xt.y, w1[k], acc[k]);
        #pragma unroll
        for (int k = 0; k < 8; ++k) acc[k] = fmaf(xt.z, w2[k], acc[k]);
        #pragma unroll
        for (int k = 0; k < 8; ++k) acc[k] = fmaf(xt.w, w3[k], acc[k]);
    }

    if (h < 3) {
        float4* fw = (float4*)(feats + (size_t)p * PPAD + c0);
        fw[0] = make_float4(acc[0], acc[1], acc[2], acc[3]);
        fw[1] = make_float4(acc[4], acc[5], acc[6], acc[7]);   // h=2: cols 22,23 exact 0
    } else {
        ((float4*)coords4)[p] = make_float4(acc[0], acc[1], acc[2], acc[3]);
        sqn[p] = fmaf(acc[0], acc[0], fmaf(acc[1], acc[1],
                 fmaf(acc[2], acc[2], acc[3] * acc[3])));
    }
}

// ---- fallback-only helpers (degenerate C > CAP path) ----------------------------
__device__ __forceinline__ void sort64_pair(float& v, int& m, int lane) {
    #pragma unroll
    for (int k = 2; k <= 64; k <<= 1) {
        #pragma unroll
        for (int j = k >> 1; j >= 1; j >>= 1) {
            float ov = __shfl_xor(v, j);
            int   om = __shfl_xor(m, j);
            bool keepMin = (((lane & j) == 0) == ((lane & k) == 0));
            bool less = (ov < v) || (ov == v && om < m);
            bool take = (less == keepMin);
            v = take ? ov : v;
            m = take ? om : m;
        }
    }
}
__device__ __forceinline__ void merge64(float& Lv, int& Lm, float cv, int cm, int lane) {
    float rv = __shfl_xor(cv, 63);
    int   rm = __shfl_xor(cm, 63);
    bool less = (rv < Lv) || (rv == Lv && rm < Lm);
    if (less) { Lv = rv; Lm = rm; }
    #pragma unroll
    for (int j = 32; j >= 1; j >>= 1) {
        float ov = __shfl_xor(Lv, j);
        int   om = __shfl_xor(Lm, j);
        bool lower = ((lane & j) == 0);
        bool l2 = (ov < Lv) || (ov == Lv && om < Lm);
        bool take = (l2 == lower);
        Lv = take ? ov : Lv;
        Lm = take ? om : Lm;
    }
}

// ---------------- per-query tail: selection + stage + aggregate + epilogue -------
// EXACT round-2 selection math (bit-identical output). cq/sq reloaded here so the
// main passes don't have to keep 16 query-coord registers live.
__device__ __forceinline__ void tail_query(
    int lane, int b, int nj, int qj, int C,
    const unsigned short* __restrict__ selq,
    const float4* __restrict__ c4, const float* __restrict__ sqb,
    const float* __restrict__ feats,
    const float* __restrict__ x, const float* __restrict__ Wo,
    const float* __restrict__ bo,
    float* __restrict__ fstage, float* __restrict__ agg,
    float* __restrict__ out)
{
    const float INF = __builtin_inff();
    const float NEGINF = -INF;
    float4 cqj = c4[nj];
    float sqnj = sqb[nj];

    if (C <= CAP) {
        unsigned kd0 = 0xFFFFFFFFu, ki0 = 0xFFFFFFFFu; float dv0 = 0.f;
        if (lane < C) {
            unsigned idx = (unsigned)selq[lane];
            float4 cm = c4[idx];
            float s2 = sqb[idx];
            float dt = fmaf(cqj.x, cm.x, fmaf(cqj.y, cm.y, fmaf(cqj.z, cm.z, cqj.w * cm.w)));
            float d  = fmaxf(fmaf(-2.f, dt, s2 + sqnj), 0.f);
            dv0 = d; kd0 = __float_as_uint(d); ki0 = idx;
        }
        unsigned kd1 = 0xFFFFFFFFu, ki1 = 0xFFFFFFFFu; float dv1 = 0.f;
        if (64 + lane < C) {
            unsigned idx = (unsigned)selq[64 + lane];
            float4 cm = c4[idx];
            float s2 = sqb[idx];
            float dt = fmaf(cqj.x, cm.x, fmaf(cqj.y, cm.y, fmaf(cqj.z, cm.z, cqj.w * cm.w)));
            float d  = fmaxf(fmaf(-2.f, dt, s2 + sqnj), 0.f);
            dv1 = d; kd1 = __float_as_uint(d); ki1 = idx;
        }
        // D = exact 39th-smallest clamped d2 bits (must stay exact)
        unsigned D = 0;
        for (int bit = 30; bit >= 0; --bit) {
            unsigned t = D | (1u << bit);
            int c = (int)__popcll(__ballot(kd0 < t))
                  + (int)__popcll(__ballot(kd1 < t));
            if (c < KSEL) D = t;
        }
        int cless  = (int)__popcll(__ballot(kd0 < D))
                   + (int)__popcll(__ballot(kd1 < D));
        int tiecnt = (int)__popcll(__ballot(kd0 == D))
                   + (int)__popcll(__ballot(kd1 == D));
        int tneed = KSEL - cless;
        unsigned TI = 0xFFFFFFFFu;
        if (tiecnt > tneed) {            // rare: resolve ties by lowest index
            unsigned pi = 0;
            for (int bit = 11; bit >= 0; --bit) {
                unsigned t = pi | (1u << bit);
                int c = (int)__popcll(__ballot((kd0 == D) && (ki0 < t)))
                      + (int)__popcll(__ballot((kd1 == D) && (ki1 < t)));
                if (c < tneed) pi = t;
            }
            TI = pi;
        }
        // stage the exactly-39 selected neighbors (ballot/prefix slots, no atomics)
        bool take0 = (kd0 < D) || ((kd0 == D) && (ki0 <= TI));
        bool take1 = (kd1 < D) || ((kd1 == D) && (ki1 <= TI));
        unsigned long long tb0 = __ballot(take0);
        unsigned long long tb1 = __ballot(take1);
        unsigned base1 = (unsigned)__popcll(tb0);
        if (take0) {
            unsigned slot = (unsigned)lane_prefix(tb0);
            float wgt = __expf(-10.f * dv0);
            const float4* fr = (const float4*)(feats + ((size_t)b * NN + ki0) * PPAD);
            float4 f0 = fr[0], f1 = fr[1], f2 = fr[2], f3 = fr[3], f4 = fr[4], f5 = fr[5];
            float4* row = (float4*)(fstage + slot * PPAD);
            row[0] = make_float4(f0.x * wgt, f0.y * wgt, f0.z * wgt, f0.w * wgt);
            row[1] = make_float4(f1.x * wgt, f1.y * wgt, f1.z * wgt, f1.w * wgt);
            row[2] = make_float4(f2.x * wgt, f2.y * wgt, f2.z * wgt, f2.w * wgt);
            row[3] = make_float4(f3.x * wgt, f3.y * wgt, f3.z * wgt, f3.w * wgt);
            row[4] = make_float4(f4.x * wgt, f4.y * wgt, f4.z * wgt, f4.w * wgt);
            row[5] = make_float4(f5.x * wgt, f5.y * wgt, f5.z * wgt, f5.w * wgt);
        }
        if (take1) {
            unsigned slot = base1 + (unsigned)lane_prefix(tb1);
            float wgt = __expf(-10.f * dv1);
            const float4* fr = (const float4*)(feats + ((size_t)b * NN + ki1) * PPAD);
            float4 f0 = fr[0], f1 = fr[1], f2 = fr[2], f3 = fr[3], f4 = fr[4], f5 = fr[5];
            float4* row = (float4*)(fstage + slot * PPAD);
            row[0] = make_float4(f0.x * wgt, f0.y * wgt, f0.z * wgt, f0.w * wgt);
            row[1] = make_float4(f1.x * wgt, f1.y * wgt, f1.z * wgt, f1.w * wgt);
            row[2] = make_float4(f2.x * wgt, f2.y * wgt, f2.z * wgt, f2.w * wgt);
            row[3] = make_float4(f3.x * wgt, f3.y * wgt, f3.z * wgt, f3.w * wgt);
            row[4] = make_float4(f4.x * wgt, f4.y * wgt, f4.z * wgt, f4.w * wgt);
            row[5] = make_float4(f5.x * wgt, f5.y * wgt, f5.z * wgt, f5.w * wgt);
        }
    } else {
        // degenerate fallback: exact streaming top-64 over all 4096
        float Lv = INF; int Lm = 0x7FFFFFFF;
        for (int c = 0; c < 64; ++c) {
            int m = c * 64 + lane;
            float4 cm = c4[m];
            float s2 = sqb[m];
            float dt = fmaf(cqj.x, cm.x, fmaf(cqj.y, cm.y, fmaf(cqj.z, cm.z, cqj.w * cm.w)));
            float v  = fmaxf(fmaf(-2.f, dt, s2 + sqnj), 0.f);
            if (m == nj) v = INF;
            sort64_pair(v, m, lane);
            if (c == 0) { Lv = v; Lm = m; }
            else        merge64(Lv, Lm, v, m, lane);
        }
        if (lane < KSEL) {
            float wgt = __expf(-10.f * Lv);
            const float4* fr = (const float4*)(feats + ((size_t)b * NN + Lm) * PPAD);
            float4 f0 = fr[0], f1 = fr[1], f2 = fr[2], f3 = fr[3], f4 = fr[4], f5 = fr[5];
            float4* row = (float4*)(fstage + lane * PPAD);
            row[0] = make_float4(f0.x * wgt, f0.y * wgt, f0.z * wgt, f0.w * wgt);
            row[1] = make_float4(f1.x * wgt, f1.y * wgt, f1.z * wgt, f1.w * wgt);
            row[2] = make_float4(f2.x * wgt, f2.y * wgt, f2.z * wgt, f2.w * wgt);
            row[3] = make_float4(f3.x * wgt, f3.y * wgt, f3.z * wgt, f3.w * wgt);
            row[4] = make_float4(f4.x * wgt, f4.y * wgt, f4.z * wgt, f4.w * wgt);
            row[5] = make_float4(f5.x * wgt, f5.y * wgt, f5.z * wgt, f5.w * wgt);
        }
    }
    WSYNC();

    // ---- max / mean over 39 neighbors: 44 lanes, split-k ----
    if (lane < 2 * PP) {
        int g  = (lane >= PP) ? 1 : 0;
        int c  = lane - g * PP;
        int k0 = g ? 20 : 0;
        int k1 = g ? KSEL : 20;
        float mx = NEGINF, sm = 0.f;
        for (int k = k0; k < k1; ++k) {
            float v = fstage[k * PPAD + c];
            mx = fmaxf(mx, v);
            sm += v;
        }
        float mx2 = __shfl(mx, lane + PP);
        float sm2 = __shfl(sm, lane + PP);
        if (lane < PP) {
            agg[c]      = fmaxf(mx, mx2);
            agg[PP + c] = (sm + sm2) * (1.f / (float)KSEL);
        }
    }
    WSYNC();

    // ---- epilogue: out = tanh([x | max | mean] @ Wo + bo), fast tanh ----
    if (lane < FOUT) {
        const float* xr  = x + (size_t)qj * FIN;
        const float* woL = Wo + lane;
        float a0 = bo[lane], a1 = 0.f, a2 = 0.f, a3 = 0.f;
        #pragma unroll
        for (int f = 0; f < FIN; f += 4) {
            a0 = fmaf(xr[f + 0], woL[(f + 0) * FOUT], a0);
            a1 = fmaf(xr[f + 1], woL[(f + 1) * FOUT], a1);
            a2 = fmaf(xr[f + 2], woL[(f + 2) * FOUT], a2);
            a3 = fmaf(xr[f + 3], woL[(f + 3) * FOUT], a3);
        }
        #pragma unroll
        for (int f = 0; f < 2 * PP; f += 4) {
            a0 = fmaf(agg[f + 0], woL[(FIN + f + 0) * FOUT], a0);
            a1 = fmaf(agg[f + 1], woL[(FIN + f + 1) * FOUT], a1);
            a2 = fmaf(agg[f + 2], woL[(FIN + f + 2) * FOUT], a2);
            a3 = fmaf(agg[f + 3], woL[(FIN + f + 3) * FOUT], a3);
        }
        float acc = (a0 + a1) + (a2 + a3);
        float e = __expf(2.f * acc);
        float r = __builtin_amdgcn_rcpf(e + 1.f);
        out[(size_t)qj * FOUT + lane] = fmaf(-2.f, r, 1.f);
    }
    WSYNC();
}

// ---------------- main: one wave per FOUR queries, e-domain passes ---------------
__global__ __launch_bounds__(WPB * 64, 8) void gn_main(
    const float* __restrict__ x,
    const float* __restrict__ Wo, const float* __restrict__ bo,
    const float* __restrict__ coords4, const float* __restrict__ sqn,
    const float* __restrict__ feats,
    float* __restrict__ out)
{
    __shared__ unsigned short sel_s[WPB * QW * CAP];     // candidate indices
    __shared__ float fstage_s[WPB * KSEL * PPAD];
    __shared__ float agg_s[WPB * 48];

    const float INF = __builtin_inff();
    const int wv    = threadIdx.x >> 6;
    const int lane  = threadIdx.x & 63;
    const int qbase = (blockIdx.x * WPB + wv) * QW;      // 4 queries, same batch
    const int b     = qbase >> 12;
    const int n0    = qbase & (NN - 1);
    unsigned short* selp = sel_s + wv * QW * CAP;
    float* fstage = fstage_s + wv * (KSEL * PPAD);
    float* agg    = agg_s + wv * 48;

    const float4* c4  = ((const float4*)coords4) + (size_t)b * NN;
    const float*  sqb = sqn + (size_t)b * NN;

    // hoisted -2*q components (query coords NOT kept live -- tails reload them).
    // e = s2 - 2*dot, a pure 4-FMA chain. Selection in e-domain (monotone shift
    // of d by -sq_j); widened bound keeps an exact superset; tail re-ranks with
    // the exact original formula, so final output is unchanged.
    float4 cq0 = c4[n0 + 0], cq1 = c4[n0 + 1], cq2 = c4[n0 + 2], cq3 = c4[n0 + 3];
    float m2x0 = -2.f * cq0.x, m2y0 = -2.f * cq0.y, m2z0 = -2.f * cq0.z, m2w0 = -2.f * cq0.w;
    float m2x1 = -2.f * cq1.x, m2y1 = -2.f * cq1.y, m2z1 = -2.f * cq1.z, m2w1 = -2.f * cq1.w;
    float m2x2 = -2.f * cq2.x, m2y2 = -2.f * cq2.y, m2z2 = -2.f * cq2.z, m2w2 = -2.f * cq2.w;
    float m2x3 = -2.f * cq3.x, m2y3 = -2.f * cq3.y, m2z3 = -2.f * cq3.z, m2w3 = -2.f * cq3.w;

    // ---- pass 1: per-query running min of e (self included) ----
    float km0 = INF, km1 = INF, km2 = INF, km3 = INF;
    #pragma unroll 4
    for (int i = 0; i < 64; ++i) {
        float4 cm = c4[i * 64 + lane];
        float s2  = sqb[i * 64 + lane];
        float e0 = fmaf(m2x0, cm.x, fmaf(m2y0, cm.y, fmaf(m2z0, cm.z, fmaf(m2w0, cm.w, s2))));
        float e1 = fmaf(m2x1, cm.x, fmaf(m2y1, cm.y, fmaf(m2z1, cm.z, fmaf(m2w1, cm.w, s2))));
        float e2 = fmaf(m2x2, cm.x, fmaf(m2y2, cm.y, fmaf(m2z2, cm.z, fmaf(m2w2, cm.w, s2))));
        float e3 = fmaf(m2x3, cm.x, fmaf(m2y3, cm.y, fmaf(m2z3, cm.z, fmaf(m2w3, cm.w, s2))));
        km0 = fminf(km0, e0);
        km1 = fminf(km1, e1);
        km2 = fminf(km2, e2);
        km3 = fminf(km3, e3);
    }
    unsigned kb0 = ford(km0), kb1 = ford(km1), kb2 = ford(km2), kb3 = ford(km3);

    // ---- bound: 40th-smallest lane-min key, TRUNCATED radix (bits 31..15),
    //      widen low 15 bits -> guaranteed >= exact 40th e. Exact superset.
    unsigned ub0 = 0, ub1 = 0, ub2 = 0, ub3 = 0;
    for (int bit = 31; bit >= 15; --bit) {
        unsigned msk = 1u << bit;
        unsigned t0 = ub0 | msk, t1 = ub1 | msk, t2 = ub2 | msk, t3 = ub3 | msk;
        if ((int)__popcll(__ballot(kb0 < t0)) < KSEL + 1) ub0 = t0;
        if ((int)__popcll(__ballot(kb1 < t1)) < KSEL + 1) ub1 = t1;
        if ((int)__popcll(__ballot(kb2 < t2)) < KSEL + 1) ub2 = t2;
        if ((int)__popcll(__ballot(kb3 < t3)) < KSEL + 1) ub3 = t3;
    }
    float UBe0 = funord(ub0 | 0x7FFFu);
    float UBe1 = funord(ub1 | 0x7FFFu);
    float UBe2 = funord(ub2 | 0x7FFFu);
    float UBe3 = funord(ub3 | 0x7FFFu);

    // selves all sit in iteration iSelf at lanes l0..l0+3 (n0 % 4 == 0)
    const int iSelf = n0 >> 6;
    const int l0    = n0 & 63;

    // ---- compact pass: ballot/prefix slot assignment (no LDS atomics) ----
    unsigned cc0 = 0, cc1 = 0, cc2 = 0, cc3 = 0;
    #pragma unroll 4
    for (int i = 0; i < 64; ++i) {
        int m = i * 64 + lane;
        float4 cm = c4[m];
        float s2  = sqb[m];
        float e0 = fmaf(m2x0, cm.x, fmaf(m2y0, cm.y, fmaf(m2z0, cm.z, fmaf(m2w0, cm.w, s2))));
        float e1 = fmaf(m2x1, cm.x, fmaf(m2y1, cm.y, fmaf(m2z1, cm.z, fmaf(m2w1, cm.w, s2))));
        float e2 = fmaf(m2x2, cm.x, fmaf(m2y2, cm.y, fmaf(m2z2, cm.z, fmaf(m2w2, cm.w, s2))));
        float e3 = fmaf(m2x3, cm.x, fmaf(m2y3, cm.y, fmaf(m2z3, cm.z, fmaf(m2w3, cm.w, s2))));
        bool t0 = (e0 <= UBe0);
        bool t1 = (e1 <= UBe1);
        bool t2 = (e2 <= UBe2);
        bool t3 = (e3 <= UBe3);
        if (i == iSelf) {                      // wave-uniform, 1 of 64 iters
            t0 = t0 && (lane != l0 + 0);
            t1 = t1 && (lane != l0 + 1);
            t2 = t2 && (lane != l0 + 2);
            t3 = t3 && (lane != l0 + 3);
        }
        unsigned long long b0 = __ballot(t0);
        unsigned long long b1 = __ballot(t1);
        unsigned long long b2 = __ballot(t2);
        unsigned long long b3 = __ballot(t3);
        if (t0) {
            unsigned s = (cc0 + (unsigned)lane_prefix(b0)) & (CAP - 1);
            selp[0 * CAP + s] = (unsigned short)m;
        }
        if (t1) {
            unsigned s = (cc1 + (unsigned)lane_prefix(b1)) & (CAP - 1);
            selp[1 * CAP + s] = (unsigned short)m;
        }
        if (t2) {
            unsigned s = (cc2 + (unsigned)lane_prefix(b2)) & (CAP - 1);
            selp[2 * CAP + s] = (unsigned short)m;
        }
        if (t3) {
            unsigned s = (cc3 + (unsigned)lane_prefix(b3)) & (CAP - 1);
            selp[3 * CAP + s] = (unsigned short)m;
        }
        cc0 += (unsigned)__popcll(b0);
        cc1 += (unsigned)__popcll(b1);
        cc2 += (unsigned)__popcll(b2);
        cc3 += (unsigned)__popcll(b3);
    }
    WSYNC();

    // ---- four explicit tail calls (no runtime-indexed private state) ----
    tail_query(lane, b, n0 + 0, qbase + 0, (int)cc0, selp + 0 * CAP,
               c4, sqb, feats, x, Wo, bo, fstage, agg, out);
    tail_query(lane, b, n0 + 1, qbase + 1, (int)cc1, selp + 1 * CAP,
               c4, sqb, feats, x, Wo, bo, fstage, agg, out);
    tail_query(lane, b, n0 + 2, qbase + 2, (int)cc2, selp + 2 * CAP,
               c4, sqb, feats, x, Wo, bo, fstage, agg, out);
    tail_query(lane, b, n0 + 3, qbase + 3, (int)cc3, selp + 3 * CAP,
               c4, sqb, feats, x, Wo, bo, fstage, agg, out);
}

extern "C" void kernel_launch(void* const* d_in, const int* in_sizes, int n_in,
                              void* d_out, int out_size, void* d_ws, size_t ws_size,
                              hipStream_t stream) {
    const float* x  = (const float*)d_in[0];
    const float* Wf = (const float*)d_in[1];
    const float* bf = (const float*)d_in[2];
    const float* Ws = (const float*)d_in[3];
    const float* bs = (const float*)d_in[4];
    const float* Wo = (const float*)d_in[5];
    const float* bo = (const float*)d_in[6];
    float* outp = (float*)d_out;

    float* ws      = (float*)d_ws;
    float* coords4 = ws;                      // 32768*4  = 131072 floats
    float* feats   = ws + 131072;             // 32768*24 = 786432 floats
    float* sqn     = ws + 131072 + 786432;    // 32768 floats

    gn_pre<<<(32768 * 4) / 256, 256, 0, stream>>>(x, Wf, bf, Ws, bs, coords4, feats, sqn);
    gn_main<<<32768 / (WPB * QW), WPB * 64, 0, stream>>>(x, Wo, bo, coords4, sqn, feats, outp);
}

// Round 6
// 155.281 us; speedup vs baseline: 3.1231x; 1.2170x over previous
//
#include <hip/hip_runtime.h>
#include <cmath>

#define NN    4096
#define FIN   32
#define KSEL  39      // neighbors kept (top-40 minus self)
#define PP    22
#define PPAD  24
#define FOUT  48
#define WPB   2       // waves per block
#define QW    4       // queries per wave
#define CAP   128     // candidate cap per query (fallback if exceeded)
#define WCOLS 32      // combined weight columns: [Wf(22) | pad(2) | Ws(4) | pad(4)]

#define WSYNC() asm volatile("s_waitcnt lgkmcnt(0)" ::: "memory")

__device__ __forceinline__ int lane_prefix(unsigned long long m) {
    return __builtin_amdgcn_mbcnt_hi((unsigned)(m >> 32),
           __builtin_amdgcn_mbcnt_lo((unsigned)m, 0));
}
// order-preserving float->uint map (total order, handles negatives)
__device__ __forceinline__ unsigned ford(float f) {
    int u = __float_as_int(f);
    return (u >= 0) ? ((unsigned)u | 0x80000000u) : ~(unsigned)u;
}
__device__ __forceinline__ float funord(unsigned k) {
    unsigned v = (k & 0x80000000u) ? (k & 0x7FFFFFFFu) : ~k;
    return __uint_as_float(v);
}
// broadcast lane l's value (l must be wave-uniform; here a literal)
__device__ __forceinline__ float lane_bcast(float v, int l) {
    return __uint_as_float((unsigned)__builtin_amdgcn_readlane((int)__float_as_uint(v), l));
}
// |c|^2 with the EXACT gn_pre FMA order (bit-identical everywhere)
__device__ __forceinline__ float sq4(float4 c) {
    return fmaf(c.x, c.x, fmaf(c.y, c.y, fmaf(c.z, c.z, c.w * c.w)));
}

// ---------------- precompute: 4 threads per point, LDS-staged weights ------------
__global__ __launch_bounds__(256) void gn_pre(
    const float* __restrict__ x,
    const float* __restrict__ Wf, const float* __restrict__ bf,
    const float* __restrict__ Ws, const float* __restrict__ bs,
    float* __restrict__ coords4, float* __restrict__ feats)
{
    __shared__ __align__(16) float sW[FIN * WCOLS];
    __shared__ float sB[WCOLS];

    int t = threadIdx.x;
    for (int idx = t; idx < FIN * WCOLS; idx += 256) {
        int i = idx >> 5, c = idx & 31;
        float v = 0.f;
        if (c < PP) v = Wf[i * PP + c];
        else if (c >= 24 && c < 28) v = Ws[i * 4 + (c - 24)];
        sW[idx] = v;
    }
    if (t < WCOLS) {
        float v = 0.f;
        if (t < PP) v = bf[t];
        else if (t >= 24 && t < 28) v = bs[t - 24];
        sB[t] = v;
    }
    __syncthreads();

    int gid = blockIdx.x * 256 + t;
    int p = gid >> 2;          // point
    int h = gid & 3;           // column strip
    int c0 = h * 8;

    const float4* xr4 = (const float4*)(x + (size_t)p * FIN);
    float acc[8];
    #pragma unroll
    for (int k = 0; k < 8; ++k) acc[k] = sB[c0 + k];

    #pragma unroll
    for (int i = 0; i < 8; ++i) {
        float4 xt = xr4[i];
        const float* w0 = sW + (4 * i + 0) * WCOLS + c0;
        const float* w1 = sW + (4 * i + 1) * WCOLS + c0;
        const float* w2 = sW + (4 * i + 2) * WCOLS + c0;
        const float* w3 = sW + (4 * i + 3) * WCOLS + c0;
        #pragma unroll
        for (int k = 0; k < 8; ++k) acc[k] = fmaf(xt.x, w0[k], acc[k]);
        #pragma unroll
        for (int k = 0; k < 8; ++k) acc[k] = fmaf(xt.y, w1[k], acc[k]);
        #pragma unroll
        for (int k = 0; k < 8; ++k) acc[k] = fmaf(xt.z, w2[k], acc[k]);
        #pragma unroll
        for (int k = 0; k < 8; ++k) acc[k] = fmaf(xt.w, w3[k], acc[k]);
    }

    if (h < 3) {
        float4* fw = (float4*)(feats + (size_t)p * PPAD + c0);
        fw[0] = make_float4(acc[0], acc[1], acc[2], acc[3]);
        fw[1] = make_float4(acc[4], acc[5], acc[6], acc[7]);   // h=2: cols 22,23 exact 0
    } else {
        ((float4*)coords4)[p] = make_float4(acc[0], acc[1], acc[2], acc[3]);
    }
}

// ---- fallback-only helpers (degenerate C > CAP path) ----------------------------
__device__ __forceinline__ void sort64_pair(float& v, int& m, int lane) {
    #pragma unroll
    for (int k = 2; k <= 64; k <<= 1) {
        #pragma unroll
        for (int j = k >> 1; j >= 1; j >>= 1) {
            float ov = __shfl_xor(v, j);
            int   om = __shfl_xor(m, j);
            bool keepMin = (((lane & j) == 0) == ((lane & k) == 0));
            bool less = (ov < v) || (ov == v && om < m);
            bool take = (less == keepMin);
            v = take ? ov : v;
            m = take ? om : m;
        }
    }
}
__device__ __forceinline__ void merge64(float& Lv, int& Lm, float cv, int cm, int lane) {
    float rv = __shfl_xor(cv, 63);
    int   rm = __shfl_xor(cm, 63);
    bool less = (rv < Lv) || (rv == Lv && rm < Lm);
    if (less) { Lv = rv; Lm = rm; }
    #pragma unroll
    for (int j = 32; j >= 1; j >>= 1) {
        float ov = __shfl_xor(Lv, j);
        int   om = __shfl_xor(Lm, j);
        bool lower = ((lane & j) == 0);
        bool l2 = (ov < Lv) || (ov == Lv && om < Lm);
        bool take = (l2 == lower);
        Lv = take ? ov : Lv;
        Lm = take ? om : Lm;
    }
}

// ------- per-query selection + staging + packed aggregate (NO epilogue here) -----
// Selection math bit-identical to the verified kernel; s2 recomputed (same bits).
// Returns packed agg: lane c<22 -> max_c ; lane 22+c -> mean_c ; others 0.
__device__ __forceinline__ float tail_select(
    int lane, int b, int nj, int C,
    const unsigned short* __restrict__ selq,
    const float4* __restrict__ c4,
    const float* __restrict__ feats,
    float* __restrict__ fstage)
{
    const float INF = __builtin_inff();
    float4 cqj = c4[nj];
    float sqnj = sq4(cqj);

    if (C <= CAP) {
        unsigned kd0 = 0xFFFFFFFFu, ki0 = 0xFFFFFFFFu; float dv0 = 0.f;
        if (lane < C) {
            unsigned idx = (unsigned)selq[lane];
            float4 cm = c4[idx];
            float s2 = sq4(cm);
            float dt = fmaf(cqj.x, cm.x, fmaf(cqj.y, cm.y, fmaf(cqj.z, cm.z, cqj.w * cm.w)));
            float d  = fmaxf(fmaf(-2.f, dt, s2 + sqnj), 0.f);
            dv0 = d; kd0 = __float_as_uint(d); ki0 = idx;
        }
        unsigned kd1 = 0xFFFFFFFFu, ki1 = 0xFFFFFFFFu; float dv1 = 0.f;
        if (64 + lane < C) {
            unsigned idx = (unsigned)selq[64 + lane];
            float4 cm = c4[idx];
            float s2 = sq4(cm);
            float dt = fmaf(cqj.x, cm.x, fmaf(cqj.y, cm.y, fmaf(cqj.z, cm.z, cqj.w * cm.w)));
            float d  = fmaxf(fmaf(-2.f, dt, s2 + sqnj), 0.f);
            dv1 = d; kd1 = __float_as_uint(d); ki1 = idx;
        }
        // D = exact 39th-smallest clamped d2 bits (must stay exact)
        unsigned D = 0;
        for (int bit = 30; bit >= 0; --bit) {
            unsigned t = D | (1u << bit);
            int c = (int)__popcll(__ballot(kd0 < t))
                  + (int)__popcll(__ballot(kd1 < t));
            if (c < KSEL) D = t;
        }
        int cless  = (int)__popcll(__ballot(kd0 < D))
                   + (int)__popcll(__ballot(kd1 < D));
        int tiecnt = (int)__popcll(__ballot(kd0 == D))
                   + (int)__popcll(__ballot(kd1 == D));
        int tneed = KSEL - cless;
        unsigned TI = 0xFFFFFFFFu;
        if (tiecnt > tneed) {            // rare: resolve ties by lowest index
            unsigned pi = 0;
            for (int bit = 11; bit >= 0; --bit) {
                unsigned t = pi | (1u << bit);
                int c = (int)__popcll(__ballot((kd0 == D) && (ki0 < t)))
                      + (int)__popcll(__ballot((kd1 == D) && (ki1 < t)));
                if (c < tneed) pi = t;
            }
            TI = pi;
        }
        // stage the exactly-39 selected neighbors (ballot/prefix slots, no atomics)
        bool take0 = (kd0 < D) || ((kd0 == D) && (ki0 <= TI));
        bool take1 = (kd1 < D) || ((kd1 == D) && (ki1 <= TI));
        unsigned long long tb0 = __ballot(take0);
        unsigned long long tb1 = __ballot(take1);
        unsigned base1 = (unsigned)__popcll(tb0);
        if (take0) {
            unsigned slot = (unsigned)lane_prefix(tb0);
            float wgt = __expf(-10.f * dv0);
            const float4* fr = (const float4*)(feats + ((size_t)b * NN + ki0) * PPAD);
            float4 f0 = fr[0], f1 = fr[1], f2 = fr[2], f3 = fr[3], f4 = fr[4], f5 = fr[5];
            float4* row = (float4*)(fstage + slot * PPAD);
            row[0] = make_float4(f0.x * wgt, f0.y * wgt, f0.z * wgt, f0.w * wgt);
            row[1] = make_float4(f1.x * wgt, f1.y * wgt, f1.z * wgt, f1.w * wgt);
            row[2] = make_float4(f2.x * wgt, f2.y * wgt, f2.z * wgt, f2.w * wgt);
            row[3] = make_float4(f3.x * wgt, f3.y * wgt, f3.z * wgt, f3.w * wgt);
            row[4] = make_float4(f4.x * wgt, f4.y * wgt, f4.z * wgt, f4.w * wgt);
            row[5] = make_float4(f5.x * wgt, f5.y * wgt, f5.z * wgt, f5.w * wgt);
        }
        if (take1) {
            unsigned slot = base1 + (unsigned)lane_prefix(tb1);
            float wgt = __expf(-10.f * dv1);
            const float4* fr = (const float4*)(feats + ((size_t)b * NN + ki1) * PPAD);
            float4 f0 = fr[0], f1 = fr[1], f2 = fr[2], f3 = fr[3], f4 = fr[4], f5 = fr[5];
            float4* row = (float4*)(fstage + slot * PPAD);
            row[0] = make_float4(f0.x * wgt, f0.y * wgt, f0.z * wgt, f0.w * wgt);
            row[1] = make_float4(f1.x * wgt, f1.y * wgt, f1.z * wgt, f1.w * wgt);
            row[2] = make_float4(f2.x * wgt, f2.y * wgt, f2.z * wgt, f2.w * wgt);
            row[3] = make_float4(f3.x * wgt, f3.y * wgt, f3.z * wgt, f3.w * wgt);
            row[4] = make_float4(f4.x * wgt, f4.y * wgt, f4.z * wgt, f4.w * wgt);
            row[5] = make_float4(f5.x * wgt, f5.y * wgt, f5.z * wgt, f5.w * wgt);
        }
    } else {
        // degenerate fallback: exact streaming top-64 over all 4096
        float Lv = INF; int Lm = 0x7FFFFFFF;
        for (int c = 0; c < 64; ++c) {
            int m = c * 64 + lane;
            float4 cm = c4[m];
            float s2 = sq4(cm);
            float dt = fmaf(cqj.x, cm.x, fmaf(cqj.y, cm.y, fmaf(cqj.z, cm.z, cqj.w * cm.w)));
            float v  = fmaxf(fmaf(-2.f, dt, s2 + sqnj), 0.f);
            if (m == nj) v = INF;
            sort64_pair(v, m, lane);
            if (c == 0) { Lv = v; Lm = m; }
            else        merge64(Lv, Lm, v, m, lane);
        }
        if (lane < KSEL) {
            float wgt = __expf(-10.f * Lv);
            const float4* fr = (const float4*)(feats + ((size_t)b * NN + Lm) * PPAD);
            float4 f0 = fr[0], f1 = fr[1], f2 = fr[2], f3 = fr[3], f4 = fr[4], f5 = fr[5];
            float4* row = (float4*)(fstage + lane * PPAD);
            row[0] = make_float4(f0.x * wgt, f0.y * wgt, f0.z * wgt, f0.w * wgt);
            row[1] = make_float4(f1.x * wgt, f1.y * wgt, f1.z * wgt, f1.w * wgt);
            row[2] = make_float4(f2.x * wgt, f2.y * wgt, f2.z * wgt, f2.w * wgt);
            row[3] = make_float4(f3.x * wgt, f3.y * wgt, f3.z * wgt, f3.w * wgt);
            row[4] = make_float4(f4.x * wgt, f4.y * wgt, f4.z * wgt, f4.w * wgt);
            row[5] = make_float4(f5.x * wgt, f5.y * wgt, f5.z * wgt, f5.w * wgt);
        }
    }
    WSYNC();

    // ---- packed aggregate over 39 neighbors: lanes 0..43 ----
    float aggv = 0.f;
    if (lane < 2 * PP) {
        int c = (lane < PP) ? lane : lane - PP;
        float mx = -INF, sm = 0.f;
        for (int k = 0; k < KSEL; ++k) {
            float v = fstage[k * PPAD + c];
            mx = fmaxf(mx, v);
            sm += v;
        }
        aggv = (lane < PP) ? mx : sm * (1.f / (float)KSEL);
    }
    WSYNC();
    return aggv;
}

// ---------------- main: one wave per FOUR queries, fused epilogue ----------------
__global__ __launch_bounds__(WPB * 64, 8) void gn_main(
    const float* __restrict__ x,
    const float* __restrict__ Wo, const float* __restrict__ bo,
    const float* __restrict__ coords4,
    const float* __restrict__ feats,
    float* __restrict__ out)
{
    __shared__ unsigned short sel_s[WPB * QW * CAP];     // candidate indices
    __shared__ float fstage_s[WPB * KSEL * PPAD];

    const float INF = __builtin_inff();
    const int wv    = threadIdx.x >> 6;
    const int lane  = threadIdx.x & 63;
    const int qbase = (blockIdx.x * WPB + wv) * QW;      // 4 queries, same batch
    const int b     = qbase >> 12;
    const int n0    = qbase & (NN - 1);
    unsigned short* selp = sel_s + wv * QW * CAP;
    float* fstage = fstage_s + wv * (KSEL * PPAD);

    const float4* c4 = ((const float4*)coords4) + (size_t)b * NN;

    // hoisted -2*q components (query coords NOT kept live -- tails reload them).
    // e = s2 - 2*dot with s2 recomputed (bit-identical chain). Selection in
    // e-domain; widened bound keeps an exact superset; tails re-rank exactly.
    float4 cq0 = c4[n0 + 0], cq1 = c4[n0 + 1], cq2 = c4[n0 + 2], cq3 = c4[n0 + 3];
    float m2x0 = -2.f * cq0.x, m2y0 = -2.f * cq0.y, m2z0 = -2.f * cq0.z, m2w0 = -2.f * cq0.w;
    float m2x1 = -2.f * cq1.x, m2y1 = -2.f * cq1.y, m2z1 = -2.f * cq1.z, m2w1 = -2.f * cq1.w;
    float m2x2 = -2.f * cq2.x, m2y2 = -2.f * cq2.y, m2z2 = -2.f * cq2.z, m2w2 = -2.f * cq2.w;
    float m2x3 = -2.f * cq3.x, m2y3 = -2.f * cq3.y, m2z3 = -2.f * cq3.z, m2w3 = -2.f * cq3.w;

    // ---- pass 1: per-query running min of e (self included) ----
    float km0 = INF, km1 = INF, km2 = INF, km3 = INF;
    #pragma unroll 4
    for (int i = 0; i < 64; ++i) {
        float4 cm = c4[i * 64 + lane];
        float s2  = sq4(cm);
        float e0 = fmaf(m2x0, cm.x, fmaf(m2y0, cm.y, fmaf(m2z0, cm.z, fmaf(m2w0, cm.w, s2))));
        float e1 = fmaf(m2x1, cm.x, fmaf(m2y1, cm.y, fmaf(m2z1, cm.z, fmaf(m2w1, cm.w, s2))));
        float e2 = fmaf(m2x2, cm.x, fmaf(m2y2, cm.y, fmaf(m2z2, cm.z, fmaf(m2w2, cm.w, s2))));
        float e3 = fmaf(m2x3, cm.x, fmaf(m2y3, cm.y, fmaf(m2z3, cm.z, fmaf(m2w3, cm.w, s2))));
        km0 = fminf(km0, e0);
        km1 = fminf(km1, e1);
        km2 = fminf(km2, e2);
        km3 = fminf(km3, e3);
    }
    unsigned kb0 = ford(km0), kb1 = ford(km1), kb2 = ford(km2), kb3 = ford(km3);

    // ---- bound: 40th-smallest lane-min key, TRUNCATED radix (bits 31..15),
    //      widen low 15 bits -> guaranteed >= exact 40th e. Exact superset.
    unsigned ub0 = 0, ub1 = 0, ub2 = 0, ub3 = 0;
    for (int bit = 31; bit >= 15; --bit) {
        unsigned msk = 1u << bit;
        unsigned t0 = ub0 | msk, t1 = ub1 | msk, t2 = ub2 | msk, t3 = ub3 | msk;
        if ((int)__popcll(__ballot(kb0 < t0)) < KSEL + 1) ub0 = t0;
        if ((int)__popcll(__ballot(kb1 < t1)) < KSEL + 1) ub1 = t1;
        if ((int)__popcll(__ballot(kb2 < t2)) < KSEL + 1) ub2 = t2;
        if ((int)__popcll(__ballot(kb3 < t3)) < KSEL + 1) ub3 = t3;
    }
    float UBe0 = funord(ub0 | 0x7FFFu);
    float UBe1 = funord(ub1 | 0x7FFFu);
    float UBe2 = funord(ub2 | 0x7FFFu);
    float UBe3 = funord(ub3 | 0x7FFFu);

    // selves all sit in iteration iSelf at lanes l0..l0+3 (n0 % 4 == 0)
    const int iSelf = n0 >> 6;
    const int l0    = n0 & 63;

    // ---- compact pass: ballot/prefix slot assignment (no LDS atomics) ----
    unsigned cc0 = 0, cc1 = 0, cc2 = 0, cc3 = 0;
    #pragma unroll 4
    for (int i = 0; i < 64; ++i) {
        int m = i * 64 + lane;
        float4 cm = c4[m];
        float s2  = sq4(cm);
        float e0 = fmaf(m2x0, cm.x, fmaf(m2y0, cm.y, fmaf(m2z0, cm.z, fmaf(m2w0, cm.w, s2))));
        float e1 = fmaf(m2x1, cm.x, fmaf(m2y1, cm.y, fmaf(m2z1, cm.z, fmaf(m2w1, cm.w, s2))));
        float e2 = fmaf(m2x2, cm.x, fmaf(m2y2, cm.y, fmaf(m2z2, cm.z, fmaf(m2w2, cm.w, s2))));
        float e3 = fmaf(m2x3, cm.x, fmaf(m2y3, cm.y, fmaf(m2z3, cm.z, fmaf(m2w3, cm.w, s2))));
        bool t0 = (e0 <= UBe0);
        bool t1 = (e1 <= UBe1);
        bool t2 = (e2 <= UBe2);
        bool t3 = (e3 <= UBe3);
        if (i == iSelf) {                      // wave-uniform, 1 of 64 iters
            t0 = t0 && (lane != l0 + 0);
            t1 = t1 && (lane != l0 + 1);
            t2 = t2 && (lane != l0 + 2);
            t3 = t3 && (lane != l0 + 3);
        }
        unsigned long long b0 = __ballot(t0);
        unsigned long long b1 = __ballot(t1);
        unsigned long long b2 = __ballot(t2);
        unsigned long long b3 = __ballot(t3);
        if (t0) {
            unsigned s = (cc0 + (unsigned)lane_prefix(b0)) & (CAP - 1);
            selp[0 * CAP + s] = (unsigned short)m;
        }
        if (t1) {
            unsigned s = (cc1 + (unsigned)lane_prefix(b1)) & (CAP - 1);
            selp[1 * CAP + s] = (unsigned short)m;
        }
        if (t2) {
            unsigned s = (cc2 + (unsigned)lane_prefix(b2)) & (CAP - 1);
            selp[2 * CAP + s] = (unsigned short)m;
        }
        if (t3) {
            unsigned s = (cc3 + (unsigned)lane_prefix(b3)) & (CAP - 1);
            selp[3 * CAP + s] = (unsigned short)m;
        }
        cc0 += (unsigned)__popcll(b0);
        cc1 += (unsigned)__popcll(b1);
        cc2 += (unsigned)__popcll(b2);
        cc3 += (unsigned)__popcll(b3);
    }
    WSYNC();

    // ---- four selection/aggregate tails (packed agg kept in VGPRs) ----
    float agg0 = tail_select(lane, b, n0 + 0, (int)cc0, selp + 0 * CAP, c4, feats, fstage);
    float agg1 = tail_select(lane, b, n0 + 1, (int)cc1, selp + 1 * CAP, c4, feats, fstage);
    float agg2 = tail_select(lane, b, n0 + 2, (int)cc2, selp + 2 * CAP, c4, feats, fstage);
    float agg3 = tail_select(lane, b, n0 + 3, (int)cc3, selp + 3 * CAP, c4, feats, fstage);

    // ---- FUSED epilogue: Wo loaded ONCE for all 4 queries; x via scalar loads ----
    const int qbU = __builtin_amdgcn_readfirstlane(qbase);
    const float* xu = x + (size_t)qbU * FIN;             // uniform -> SMEM loads
    if (lane < FOUT) {
        const float* woL = Wo + lane;
        float bb = bo[lane];
        float a00 = bb, a01 = 0.f, a02 = 0.f, a03 = 0.f;
        float a10 = bb, a11 = 0.f, a12 = 0.f, a13 = 0.f;
        float a20 = bb, a21 = 0.f, a22 = 0.f, a23 = 0.f;
        float a30 = bb, a31 = 0.f, a32 = 0.f, a33 = 0.f;
        #pragma unroll
        for (int f = 0; f < FIN; f += 4) {
            float w0 = woL[(f + 0) * FOUT];
            float w1 = woL[(f + 1) * FOUT];
            float w2 = woL[(f + 2) * FOUT];
            float w3 = woL[(f + 3) * FOUT];
            a00 = fmaf(xu[0 * FIN + f + 0], w0, a00);
            a01 = fmaf(xu[0 * FIN + f + 1], w1, a01);
            a02 = fmaf(xu[0 * FIN + f + 2], w2, a02);
            a03 = fmaf(xu[0 * FIN + f + 3], w3, a03);
            a10 = fmaf(xu[1 * FIN + f + 0], w0, a10);
            a11 = fmaf(xu[1 * FIN + f + 1], w1, a11);
            a12 = fmaf(xu[1 * FIN + f + 2], w2, a12);
            a13 = fmaf(xu[1 * FIN + f + 3], w3, a13);
            a20 = fmaf(xu[2 * FIN + f + 0], w0, a20);
            a21 = fmaf(xu[2 * FIN + f + 1], w1, a21);
            a22 = fmaf(xu[2 * FIN + f + 2], w2, a22);
            a23 = fmaf(xu[2 * FIN + f + 3], w3, a23);
            a30 = fmaf(xu[3 * FIN + f + 0], w0, a30);
            a31 = fmaf(xu[3 * FIN + f + 1], w1, a31);
            a32 = fmaf(xu[3 * FIN + f + 2], w2, a32);
            a33 = fmaf(xu[3 * FIN + f + 3], w3, a33);
        }
        #pragma unroll
        for (int g = 0; g < 2 * PP; g += 4) {
            float w0 = woL[(FIN + g + 0) * FOUT];
            float w1 = woL[(FIN + g + 1) * FOUT];
            float w2 = woL[(FIN + g + 2) * FOUT];
            float w3 = woL[(FIN + g + 3) * FOUT];
            a00 = fmaf(lane_bcast(agg0, g + 0), w0, a00);
            a01 = fmaf(lane_bcast(agg0, g + 1), w1, a01);
            a02 = fmaf(lane_bcast(agg0, g + 2), w2, a02);
            a03 = fmaf(lane_bcast(agg0, g + 3), w3, a03);
            a10 = fmaf(lane_bcast(agg1, g + 0), w0, a10);
            a11 = fmaf(lane_bcast(agg1, g + 1), w1, a11);
            a12 = fmaf(lane_bcast(agg1, g + 2), w2, a12);
            a13 = fmaf(lane_bcast(agg1, g + 3), w3, a13);
            a20 = fmaf(lane_bcast(agg2, g + 0), w0, a20);
            a21 = fmaf(lane_bcast(agg2, g + 1), w1, a21);
            a22 = fmaf(lane_bcast(agg2, g + 2), w2, a22);
            a23 = fmaf(lane_bcast(agg2, g + 3), w3, a23);
            a30 = fmaf(lane_bcast(agg3, g + 0), w0, a30);
            a31 = fmaf(lane_bcast(agg3, g + 1), w1, a31);
            a32 = fmaf(lane_bcast(agg3, g + 2), w2, a32);
            a33 = fmaf(lane_bcast(agg3, g + 3), w3, a33);
        }
        float ac0 = (a00 + a01) + (a02 + a03);
        float ac1 = (a10 + a11) + (a12 + a13);
        float ac2 = (a20 + a21) + (a22 + a23);
        float ac3 = (a30 + a31) + (a32 + a33);
        float e0 = __expf(2.f * ac0);
        float e1 = __expf(2.f * ac1);
        float e2 = __expf(2.f * ac2);
        float e3 = __expf(2.f * ac3);
        float r0 = __builtin_amdgcn_rcpf(e0 + 1.f);
        float r1 = __builtin_amdgcn_rcpf(e1 + 1.f);
        float r2 = __builtin_amdgcn_rcpf(e2 + 1.f);
        float r3 = __builtin_amdgcn_rcpf(e3 + 1.f);
        out[(size_t)(qbU + 0) * FOUT + lane] = fmaf(-2.f, r0, 1.f);
        out[(size_t)(qbU + 1) * FOUT + lane] = fmaf(-2.f, r1, 1.f);
        out[(size_t)(qbU + 2) * FOUT + lane] = fmaf(-2.f, r2, 1.f);
        out[(size_t)(qbU + 3) * FOUT + lane] = fmaf(-2.f, r3, 1.f);
    }
}

extern "C" void kernel_launch(void* const* d_in, const int* in_sizes, int n_in,
                              void* d_out, int out_size, void* d_ws, size_t ws_size,
                              hipStream_t stream) {
    const float* x  = (const float*)d_in[0];
    const float* Wf = (const float*)d_in[1];
    const float* bf = (const float*)d_in[2];
    const float* Ws = (const float*)d_in[3];
    const float* bs = (const float*)d_in[4];
    const float* Wo = (const float*)d_in[5];
    const float* bo = (const float*)d_in[6];
    float* outp = (float*)d_out;

    float* ws      = (float*)d_ws;
    float* coords4 = ws;                      // 32768*4  = 131072 floats
    float* feats   = ws + 131072;             // 32768*24 = 786432 floats

    gn_pre<<<(32768 * 4) / 256, 256, 0, stream>>>(x, Wf, bf, Ws, bs, coords4, feats);
    gn_main<<<32768 / (WPB * QW), WPB * 64, 0, stream>>>(x, Wo, bo, coords4, feats, outp);
}